// Round 4
// baseline (866.609 us; speedup 1.0000x reference)
//
#include <hip/hip_runtime.h>
#include <math.h>

// ---------------------------------------------------------------------------
// GNN: 3x GCNConv(edge-weighted, self-loops) + SiLU, mean-pool, MLP.
// R1-R11: CSR-by-dst, fused gather+xform, two-stage pool, padded buckets. 540us
// R12: nt-hints REGRESSED (707). R13: revert (545.4).
// R14: fp16 feature storage xp/h1s/h2s. 545 -> 477us, absmax 4.8e-7.
// R15: layer-3 as MFMA f16, W-frags in registers, no LDS. 477 -> 433.6us.
// R16: NBH 256->1024: occ 9->33% but bscatter UNCHANGED (~80us) -> scatter
//      cost is parallelism-invariant (per-edge scattered 8B stores, partial-
//      sector WRITE 47->90MB). 433.6 -> 430.1us.
// R17 (this round): pay the scatter ONCE, not twice. Drop ebuf+bscatter+
//      bucket_csr; new: k_count (global atomics ncnt/wsum, 6.4M LLC atomics
//      over 800KB), k_nodeprep (exact per-node prefix in-bucket -> offs/curs
//      + dinv + xp), k_escatter (single scatter: pos=atomicAdd(curs[dst]),
//      csr[pos]={src,ew}). Zeroing folded into grid-strided k_init.
//      Predict: 80+~45 -> ~15+~8+~55; total ~380us.
// ---------------------------------------------------------------------------

#define NSC 2048      // grid-stride blocks for count/escatter
#define POOL_C 8      // chunks per graph for fused GEMM+pool (512 blocks = 2/CU)
#define CAP 10240     // padded bucket capacity (mean 8184, sigma~90)

typedef _Float16 half8 __attribute__((ext_vector_type(8)));
typedef float f32x4 __attribute__((ext_vector_type(4)));

__device__ __forceinline__ float silu_f(float v) { return v / (1.0f + expf(-v)); }

// ---- init: zero ncnt/wsum (grid-strided) + graph boundaries (block 0) ----
__global__ __launch_bounds__(256) void k_init(const int* __restrict__ batch,
                                              int* __restrict__ bounds,
                                              int* __restrict__ ncnt,
                                              float* __restrict__ wsum,
                                              int N, int G) {
    int i = blockIdx.x * 256 + threadIdx.x;
    int stride = gridDim.x * 256;
    for (int k = i; k < N; k += stride) { ncnt[k] = 0; wsum[k] = 0.0f; }
    if (blockIdx.x == 0) {
        int t = threadIdx.x;
        if (t > G) return;
        if (t == G) { bounds[G] = N; return; }
        int lo = 0, hi = N;
        while (lo < hi) { int m = (lo + hi) >> 1; if (batch[m] < t) lo = m + 1; else hi = m; }
        bounds[t] = lo;
    }
}

// ---- per-node degree + weight-sum via LLC atomics ----
__global__ __launch_bounds__(256) void k_count(const int* __restrict__ dst,
                                               const float* __restrict__ ew,
                                               int* __restrict__ ncnt,
                                               float* __restrict__ wsum, int E) {
    int e = blockIdx.x * 256 + threadIdx.x;
    int stride = gridDim.x * 256;
    for (; e < E; e += stride) {
        int d = dst[e];
        atomicAdd(&ncnt[d], 1);
        atomicAdd(&wsum[d], ew[e]);
    }
}

// ---- in-bucket exact prefix -> packed offs + cursors + dinv + xp(fp16) ----
__global__ __launch_bounds__(256) void k_nodeprep(const int* __restrict__ ncnt,
                                                  const float* __restrict__ wsum,
                                                  unsigned int* __restrict__ offs,
                                                  int* __restrict__ curs,
                                                  float* __restrict__ dinv,
                                                  const float* __restrict__ x,
                                                  _Float16* __restrict__ xp,
                                                  int N) {
    __shared__ int excl[256];
    int b = blockIdx.x, t = threadIdx.x;
    int n = (b << 8) + t;
    int v = (n < N) ? ncnt[n] : 0;
    excl[t] = v;
    __syncthreads();
#pragma unroll
    for (int o = 1; o < 256; o <<= 1) {
        int x2 = (t >= o) ? excl[t - o] : 0;
        __syncthreads();
        excl[t] += x2;
        __syncthreads();
    }
    int ex = excl[t] - v;                 // exclusive prefix within bucket
    int base = b * CAP;
    if (n < N) {
        offs[n] = (unsigned)(base + ex) | ((unsigned)v << 24);
        curs[n] = base + ex;
        float dv = 1.0f / sqrtf(1.0f + wsum[n]);
        dinv[n] = dv;
        const float4* xr = (const float4*)(x + (long long)n * 16);
        half8* xw = (half8*)(xp + (long long)n * 16);
#pragma unroll
        for (int j = 0; j < 2; j++) {
            float4 a = xr[2 * j], c = xr[2 * j + 1];
            half8 hv;
            hv[0] = (_Float16)(a.x * dv); hv[1] = (_Float16)(a.y * dv);
            hv[2] = (_Float16)(a.z * dv); hv[3] = (_Float16)(a.w * dv);
            hv[4] = (_Float16)(c.x * dv); hv[5] = (_Float16)(c.y * dv);
            hv[6] = (_Float16)(c.z * dv); hv[7] = (_Float16)(c.w * dv);
            xw[j] = hv;
        }
    }
}

// ---- single scatter pass: edge -> final CSR slot ----
__global__ __launch_bounds__(256) void k_escatter(const int* __restrict__ src,
                                                  const int* __restrict__ dst,
                                                  const float* __restrict__ ew,
                                                  int* __restrict__ curs,
                                                  int2* __restrict__ csr,
                                                  int E, int limit) {
    int e = blockIdx.x * 256 + threadIdx.x;
    int stride = gridDim.x * 256;
    for (; e < E; e += stride) {
        int d = dst[e];
        int pos = atomicAdd(&curs[d], 1);
        if (pos < limit)
            csr[pos] = make_int2(src[e], __float_as_int(ew[e]));
    }
}

// ---- fused gather16 + 16->16 GEMM + silu: h1 = silu(y@W1+b1)*dinv (fp16 io) ----
// Edge-group eg owns a CONTIGUOUS quarter of the row, ILP8.
__global__ __launch_bounds__(256) void k_gx1(const _Float16* __restrict__ h,
                                             const int2* __restrict__ csr,
                                             const unsigned int* __restrict__ offs,
                                             const float* __restrict__ dinv,
                                             const float* __restrict__ W,
                                             const float* __restrict__ b,
                                             _Float16* __restrict__ out, int N) {
    __shared__ float Ws[16 * 16];
    __shared__ float bs[16];
    if (threadIdx.x < 256) Ws[threadIdx.x] = W[threadIdx.x];
    if (threadIdx.x < 16) bs[threadIdx.x] = b[threadIdx.x];
    __syncthreads();
    int n = blockIdx.x * 4 + (threadIdx.x >> 6);
    n = __builtin_amdgcn_readfirstlane(n);
    if (n >= N) return;
    int lane = threadIdx.x & 63;
    int d = lane & 15, eg = lane >> 4;
    unsigned op = offs[n];
    int p0 = op & 0x00FFFFFF;
    int len = op >> 24;
    int qs = p0 + ((len * eg) >> 2);
    int qe = p0 + ((len * (eg + 1)) >> 2);
    float acc = 0.0f;
    int p = qs;
    for (; p + 7 < qe; p += 8) {
        int2 e0 = csr[p], e1 = csr[p + 1], e2 = csr[p + 2], e3 = csr[p + 3];
        int2 e4 = csr[p + 4], e5 = csr[p + 5], e6 = csr[p + 6], e7 = csr[p + 7];
        float v0 = (float)h[e0.x * 16 + d], v1 = (float)h[e1.x * 16 + d];
        float v2 = (float)h[e2.x * 16 + d], v3 = (float)h[e3.x * 16 + d];
        float v4 = (float)h[e4.x * 16 + d], v5 = (float)h[e5.x * 16 + d];
        float v6 = (float)h[e6.x * 16 + d], v7 = (float)h[e7.x * 16 + d];
        acc += __int_as_float(e0.y) * v0; acc += __int_as_float(e1.y) * v1;
        acc += __int_as_float(e2.y) * v2; acc += __int_as_float(e3.y) * v3;
        acc += __int_as_float(e4.y) * v4; acc += __int_as_float(e5.y) * v5;
        acc += __int_as_float(e6.y) * v6; acc += __int_as_float(e7.y) * v7;
    }
    if (p + 3 < qe) {
        int2 e0 = csr[p], e1 = csr[p + 1], e2 = csr[p + 2], e3 = csr[p + 3];
        float v0 = (float)h[e0.x * 16 + d], v1 = (float)h[e1.x * 16 + d];
        float v2 = (float)h[e2.x * 16 + d], v3 = (float)h[e3.x * 16 + d];
        acc += __int_as_float(e0.y) * v0; acc += __int_as_float(e1.y) * v1;
        acc += __int_as_float(e2.y) * v2; acc += __int_as_float(e3.y) * v3;
        p += 4;
    }
    if (p + 1 < qe) {
        int2 e0 = csr[p], e1 = csr[p + 1];
        acc += __int_as_float(e0.y) * (float)h[e0.x * 16 + d];
        acc += __int_as_float(e1.y) * (float)h[e1.x * 16 + d];
        p += 2;
    }
    if (p < qe) {
        int2 e0 = csr[p];
        acc += __int_as_float(e0.y) * (float)h[e0.x * 16 + d];
    }
    acc += __shfl_down(acc, 32, 64);
    acc += __shfl_down(acc, 16, 64);
    float dv = dinv[n];
    float yv = (acc + ((lane < 16) ? (float)h[n * 16 + lane] : 0.0f)) * dv;
    float o = bs[d];
#pragma unroll
    for (int k = 0; k < 16; k++) o += __shfl(yv, k, 64) * Ws[k * 16 + d];
    if (lane < 16) out[n * 16 + lane] = (_Float16)(silu_f(o) * dv);
}

// ---- fused gather16 + 16->64 GEMM + silu: h2 = silu(y@W2+b2)*dinv (fp16 io) ----
__global__ __launch_bounds__(256) void k_gx2(const _Float16* __restrict__ h,
                                             const int2* __restrict__ csr,
                                             const unsigned int* __restrict__ offs,
                                             const float* __restrict__ dinv,
                                             const float* __restrict__ W,
                                             const float* __restrict__ b,
                                             _Float16* __restrict__ out, int N) {
    __shared__ float Ws[16 * 64];
    __shared__ float bs[64];
    for (int i = threadIdx.x; i < 16 * 64; i += 256) Ws[i] = W[i];
    if (threadIdx.x < 64) bs[threadIdx.x] = b[threadIdx.x];
    __syncthreads();
    int n = blockIdx.x * 4 + (threadIdx.x >> 6);
    n = __builtin_amdgcn_readfirstlane(n);
    if (n >= N) return;
    int lane = threadIdx.x & 63;
    int d = lane & 15, eg = lane >> 4;
    unsigned op = offs[n];
    int p0 = op & 0x00FFFFFF;
    int len = op >> 24;
    int qs = p0 + ((len * eg) >> 2);
    int qe = p0 + ((len * (eg + 1)) >> 2);
    float acc = 0.0f;
    int p = qs;
    for (; p + 7 < qe; p += 8) {
        int2 e0 = csr[p], e1 = csr[p + 1], e2 = csr[p + 2], e3 = csr[p + 3];
        int2 e4 = csr[p + 4], e5 = csr[p + 5], e6 = csr[p + 6], e7 = csr[p + 7];
        float v0 = (float)h[e0.x * 16 + d], v1 = (float)h[e1.x * 16 + d];
        float v2 = (float)h[e2.x * 16 + d], v3 = (float)h[e3.x * 16 + d];
        float v4 = (float)h[e4.x * 16 + d], v5 = (float)h[e5.x * 16 + d];
        float v6 = (float)h[e6.x * 16 + d], v7 = (float)h[e7.x * 16 + d];
        acc += __int_as_float(e0.y) * v0; acc += __int_as_float(e1.y) * v1;
        acc += __int_as_float(e2.y) * v2; acc += __int_as_float(e3.y) * v3;
        acc += __int_as_float(e4.y) * v4; acc += __int_as_float(e5.y) * v5;
        acc += __int_as_float(e6.y) * v6; acc += __int_as_float(e7.y) * v7;
    }
    if (p + 3 < qe) {
        int2 e0 = csr[p], e1 = csr[p + 1], e2 = csr[p + 2], e3 = csr[p + 3];
        float v0 = (float)h[e0.x * 16 + d], v1 = (float)h[e1.x * 16 + d];
        float v2 = (float)h[e2.x * 16 + d], v3 = (float)h[e3.x * 16 + d];
        acc += __int_as_float(e0.y) * v0; acc += __int_as_float(e1.y) * v1;
        acc += __int_as_float(e2.y) * v2; acc += __int_as_float(e3.y) * v3;
        p += 4;
    }
    if (p + 1 < qe) {
        int2 e0 = csr[p], e1 = csr[p + 1];
        acc += __int_as_float(e0.y) * (float)h[e0.x * 16 + d];
        acc += __int_as_float(e1.y) * (float)h[e1.x * 16 + d];
        p += 2;
    }
    if (p < qe) {
        int2 e0 = csr[p];
        acc += __int_as_float(e0.y) * (float)h[e0.x * 16 + d];
    }
    acc += __shfl_down(acc, 32, 64);
    acc += __shfl_down(acc, 16, 64);
    float dv = dinv[n];
    float yv = (acc + ((lane < 16) ? (float)h[n * 16 + lane] : 0.0f)) * dv;
    float o = bs[lane];
#pragma unroll
    for (int k = 0; k < 16; k++) o += __shfl(yv, k, 64) * Ws[k * 64 + lane];
    out[(long long)n * 64 + lane] = (_Float16)(silu_f(o) * dv);
}

// ---- gather D=64 fp16 rows (128B = 1 line) + self term; fp16 y out ----
__global__ __launch_bounds__(256) void k_gather64(const _Float16* __restrict__ h,
                                                  const int2* __restrict__ csr,
                                                  const unsigned int* __restrict__ offs,
                                                  const float* __restrict__ dinv,
                                                  _Float16* __restrict__ y, int N) {
    int n = blockIdx.x * 4 + (threadIdx.x >> 6);
    n = __builtin_amdgcn_readfirstlane(n);
    if (n >= N) return;
    int lane = threadIdx.x & 63;
    unsigned op = offs[n];
    const int2* row = csr + (op & 0x00FFFFFF);
    int len = op >> 24;
    float acc = 0.0f;
    int j = 0;
    for (; j + 7 < len; j += 8) {
        int2 ee[8];
        float vv[8];
#pragma unroll
        for (int i = 0; i < 8; i++) ee[i] = row[j + i];
#pragma unroll
        for (int i = 0; i < 8; i++) vv[i] = (float)h[ee[i].x * 64 + lane];
#pragma unroll
        for (int i = 0; i < 8; i++) acc += __int_as_float(ee[i].y) * vv[i];
    }
    if (j + 3 < len) {                     // ILP 4 tail
        int2 e0 = row[j], e1 = row[j + 1], e2 = row[j + 2], e3 = row[j + 3];
        float v0 = (float)h[e0.x * 64 + lane];
        float v1 = (float)h[e1.x * 64 + lane];
        float v2 = (float)h[e2.x * 64 + lane];
        float v3 = (float)h[e3.x * 64 + lane];
        acc += __int_as_float(e0.y) * v0;
        acc += __int_as_float(e1.y) * v1;
        acc += __int_as_float(e2.y) * v2;
        acc += __int_as_float(e3.y) * v3;
        j += 4;
    }
    for (; j < len; j++) {
        int2 e0 = row[j];
        acc += __int_as_float(e0.y) * (float)h[e0.x * 64 + lane];
    }
    y[n * 64 + lane] = (_Float16)((acc + (float)h[n * 64 + lane]) * dinv[n]);
}

// ---- layer-3 via MFMA f16: GEMM [ce-cs,64]@[64,256] + bias + silu + pool ----
// Wave owns out-tiles wave*4..wave*4+3. W3 read as f32, converted to f16
// B-frags in registers (64KB L2-hot), reused across all node tiles. A-frags
// direct from global y (L1-hot). No LDS, no barriers.
// Frag layouts: A row=lane&15, k=8*(lane>>4)+j; B col=lane&15, same k;
// C/D col=lane&15, row=4*(lane>>4)+reg (m89-verified).
__global__ __launch_bounds__(256) void k_xform3pool(const _Float16* __restrict__ y,
                                                    const float* __restrict__ W,
                                                    const float* __restrict__ b,
                                                    const int* __restrict__ bounds,
                                                    float* __restrict__ partial,
                                                    int N) {
    int lane = threadIdx.x & 63;
    int wave = threadIdx.x >> 6;
    int g = blockIdx.x / POOL_C;
    int c = blockIdx.x % POOL_C;
    int s = bounds[g], e = bounds[g + 1];
    int len = e - s;
    int cs = s + (int)((long long)len * c / POOL_C);
    int ce = s + (int)((long long)len * (c + 1) / POOL_C);
    int lg = lane >> 4;        // lane-group (k-block for A/B, row-block for C)
    int lr = lane & 15;        // A row / B,C col

    half8 bf[4][2];            // [out-tile][kstep] W fragments, in registers
#pragma unroll
    for (int t = 0; t < 4; t++) {
        int col = (wave * 4 + t) * 16 + lr;
#pragma unroll
        for (int s2 = 0; s2 < 2; s2++) {
            half8 v;
#pragma unroll
            for (int j = 0; j < 8; j++)
                v[j] = (_Float16)W[(s2 * 32 + lg * 8 + j) * 256 + col];
            bf[t][s2] = v;
        }
    }
    float bias[4];
#pragma unroll
    for (int t = 0; t < 4; t++) bias[t] = b[(wave * 4 + t) * 16 + lr];

    float pacc[4] = {0.f, 0.f, 0.f, 0.f};

    for (int base = cs; base < ce; base += 16) {
        int node = base + lr;
        int cn = node < N ? node : N - 1;      // clamp addr; masked at pool
        const half8* arow = (const half8*)(y + (long long)cn * 64);
        half8 a0 = arow[lg];                   // k = 0..31, this group's 8
        half8 a1 = arow[4 + lg];               // k = 32..63
#pragma unroll
        for (int t = 0; t < 4; t++) {
            f32x4 acc = {0.f, 0.f, 0.f, 0.f};
            acc = __builtin_amdgcn_mfma_f32_16x16x32_f16(a0, bf[t][0], acc, 0, 0, 0);
            acc = __builtin_amdgcn_mfma_f32_16x16x32_f16(a1, bf[t][1], acc, 0, 0, 0);
#pragma unroll
            for (int r = 0; r < 4; r++) {
                int nrow = base + lg * 4 + r;  // C row -> node
                if (nrow < ce) pacc[t] += silu_f(acc[r] + bias[t]);
            }
        }
    }
    // reduce over the 4 row-groups: lanes sharing lr
#pragma unroll
    for (int t = 0; t < 4; t++) {
        pacc[t] += __shfl_xor(pacc[t], 16, 64);
        pacc[t] += __shfl_xor(pacc[t], 32, 64);
    }
    if (lane < 16) {
        float* pr = partial + (long long)blockIdx.x * 256 + wave * 64;
#pragma unroll
        for (int t = 0; t < 4; t++) pr[t * 16 + lane] = pacc[t];
    }
}

// ---- pool stage 2 + MLP ----
__global__ __launch_bounds__(256) void k_mlp(const float* __restrict__ partial,
                                             const int* __restrict__ bounds,
                                             const float* __restrict__ L1,
                                             const float* __restrict__ c1,
                                             const float* __restrict__ L2,
                                             const float* __restrict__ c2,
                                             const float* __restrict__ L3,
                                             const float* __restrict__ c3,
                                             float* __restrict__ out) {
    __shared__ float pooled[256];
    __shared__ float z1[128];
    __shared__ float z2[64];
    int g = blockIdx.x;
    int t = threadIdx.x;
    int cnt = bounds[g + 1] - bounds[g];
    float s = 0.0f;
    for (int c = 0; c < POOL_C; c++) s += partial[((long long)g * POOL_C + c) * 256 + t];
    pooled[t] = s / (float)(cnt > 0 ? cnt : 1);
    __syncthreads();
    if (t < 128) {
        float acc = c1[t];
        for (int k = 0; k < 256; k++) acc += pooled[k] * L1[k * 128 + t];
        z1[t] = silu_f(acc);
    }
    __syncthreads();
    if (t < 64) {
        float acc = c2[t];
        for (int k = 0; k < 128; k++) acc += z1[k] * L2[k * 64 + t];
        z2[t] = silu_f(acc);
    }
    __syncthreads();
    if (t < 3) {
        float acc = c3[t];
        for (int k = 0; k < 64; k++) acc += z2[k] * L3[k * 3 + t];
        out[g * 3 + t] = acc;
    }
}

extern "C" void kernel_launch(void* const* d_in, const int* in_sizes, int n_in,
                              void* d_out, int out_size, void* d_ws, size_t ws_size,
                              hipStream_t stream) {
    const float* x     = (const float*)d_in[0];
    const int*   ei    = (const int*)d_in[1];
    const float* ea    = (const float*)d_in[2];
    const int*   batch = (const int*)d_in[3];
    const float* W1 = (const float*)d_in[4];
    const float* b1 = (const float*)d_in[5];
    const float* W2 = (const float*)d_in[6];
    const float* b2 = (const float*)d_in[7];
    const float* W3 = (const float*)d_in[8];
    const float* b3 = (const float*)d_in[9];
    const float* L1 = (const float*)d_in[10];
    const float* c1 = (const float*)d_in[11];
    const float* L2 = (const float*)d_in[12];
    const float* c2 = (const float*)d_in[13];
    const float* L3 = (const float*)d_in[14];
    const float* c3 = (const float*)d_in[15];
    float* out = (float*)d_out;

    const int N = in_sizes[0] / 16;
    const int E = in_sizes[2];
    const int G = out_size / 3;
    const int* src = ei;
    const int* dst = ei + E;
    const int B = (N + 255) >> 8;               // buckets (<=512)

    char* ws = (char*)d_ws;
    size_t off = 0;
    auto alloc = [&](size_t bytes) -> void* {
        void* p = (void*)(ws + off);
        off += (bytes + 255) & ~(size_t)255;
        return p;
    };
    float*        dinv    = (float*)alloc((size_t)N * 4);
    unsigned int* offs    = (unsigned int*)alloc((size_t)N * 4);
    int*          ncnt    = (int*)  alloc((size_t)N * 4);
    float*        wsum    = (float*)alloc((size_t)N * 4);
    int*          curs    = (int*)  alloc((size_t)N * 4);
    int*          bounds  = (int*)  alloc((size_t)(G + 1) * 4);
    int2*         csr     = (int2*) alloc((size_t)B * CAP * 8);   // padded CSR
    _Float16*     xp      = (_Float16*)alloc((size_t)N * 16 * 2);
    _Float16*     h1s     = (_Float16*)alloc((size_t)N * 16 * 2);
    _Float16*     h2s     = (_Float16*)alloc((size_t)N * 64 * 2);
    _Float16*     y64     = (_Float16*)alloc((size_t)N * 64 * 2);
    float*        partial = (float*)alloc((size_t)G * POOL_C * 256 * 4);
    (void)ws_size;

    // ---- CSR build: count -> per-node offsets -> single scatter ----
    k_init<<<256, 256, 0, stream>>>(batch, bounds, ncnt, wsum, N, G);
    k_count<<<NSC, 256, 0, stream>>>(dst, ea, ncnt, wsum, E);
    k_nodeprep<<<B, 256, 0, stream>>>(ncnt, wsum, offs, curs, dinv, x, xp, N);
    k_escatter<<<NSC, 256, 0, stream>>>(src, dst, ea, curs, csr, E, B * CAP);

    // ---- layer 1 (fused gather+xform) ----
    k_gx1<<<(N + 3) / 4, 256, 0, stream>>>(xp, csr, offs, dinv, W1, b1, h1s, N);

    // ---- layer 2 (fused gather+xform) ----
    k_gx2<<<(N + 3) / 4, 256, 0, stream>>>(h1s, csr, offs, dinv, W2, b2, h2s, N);

    // ---- layer 3: gather fp16, then MFMA GEMM+silu+pool (h3 never written) ----
    k_gather64<<<(N + 3) / 4, 256, 0, stream>>>(h2s, csr, offs, dinv, y64, N);
    k_xform3pool<<<G * POOL_C, 256, 0, stream>>>(y64, W3, b3, bounds, partial, N);

    // ---- MLP head ----
    k_mlp<<<G, 256, 0, stream>>>(partial, bounds, L1, c1, L2, c2, L3, c3, out);
}

// Round 5
// 426.915 us; speedup vs baseline: 2.0299x; 2.0299x over previous
//
#include <hip/hip_runtime.h>
#include <math.h>

// ---------------------------------------------------------------------------
// GNN: 3x GCNConv(edge-weighted, self-loops) + SiLU, mean-pool, MLP.
// R1-R11: CSR-by-dst, fused gather+xform, two-stage pool, padded buckets. 540us
// R12: nt-hints REGRESSED (707). R13: revert (545.4).
// R14: fp16 feature storage xp/h1s/h2s. 545 -> 477us, absmax 4.8e-7.
// R15: layer-3 as MFMA f16, W-frags in registers, no LDS. 477 -> 433.6us.
// R16: NBH 256->1024: occ 9->33% but bscatter UNCHANGED -> per-edge scatter
//      cost is per-CU-work-invariant (LDS RMW + scattered-store issue).
// R17: global-atomic CSR build REGRESSED HARD (k_count 279us: random global
//      atomics ~46M/s, 40x worse than LDS hist). REVERT to R16 structure.
// R18 (this round): 4-byte packed CSR entries: src 17b | ew fp16 15b (ew>=0,
//      sign dropped). Halves csr stream read by gx1/gx2/gather64 (3x25.6
//      -> 3x12.8MB), halves bucket_csr scatter payload, and csr+h2s now
//      fit aggregate L2 during gather64. dinv/wsum still fp32-exact.
//      Predict total 430 -> ~400us, absmax ~2-5e-5 (pool-averaged fp16 ew).
// ---------------------------------------------------------------------------

#define NBH 1024      // scatter blocks (4/CU)
#define POOL_C 8      // chunks per graph for fused GEMM+pool (512 blocks = 2/CU)
#define CAP 10240     // padded bucket capacity (mean 8184, sigma~90)

typedef _Float16 half8 __attribute__((ext_vector_type(8)));
typedef float f32x4 __attribute__((ext_vector_type(4)));

__device__ __forceinline__ float silu_f(float v) { return v / (1.0f + expf(-v)); }

// ---- packed CSR entry helpers: u = (src<<15) | (fp16(ew) & 0x7FFF) ----
__device__ __forceinline__ int psrc(unsigned u) { return (int)(u >> 15); }
__device__ __forceinline__ float pew(unsigned u) {
    unsigned short hs = (unsigned short)(u & 0x7FFFu);
    _Float16 hv;
    __builtin_memcpy(&hv, &hs, 2);
    return (float)hv;
}
__device__ __forceinline__ unsigned packent(int src, float w) {
    _Float16 hw = (_Float16)w;
    unsigned short hb;
    __builtin_memcpy(&hb, &hw, 2);
    return ((unsigned)src << 15) | (unsigned)(hb & 0x7FFFu);
}

// ---- init: zero bucket cursors + graph boundaries (one tiny block) ----
__global__ void k_init(const int* __restrict__ batch, int* __restrict__ bounds,
                       int* __restrict__ btotal, int N, int G) {
    int t = threadIdx.x;
    btotal[t] = 0;                     // 512 threads, 512 ints
    if (t > G) return;
    if (t == G) { bounds[G] = N; return; }
    int lo = 0, hi = N;
    while (lo < hi) { int m = (lo + hi) >> 1; if (batch[m] < t) lo = m + 1; else hi = m; }
    bounds[t] = lo;
}

// ---- count + reserve + scatter into statically-based padded buckets ----
__global__ __launch_bounds__(256) void k_bscatter(const int* __restrict__ src,
                                                  const int* __restrict__ dst,
                                                  const float* __restrict__ ew,
                                                  int* __restrict__ btotal,
                                                  int2* __restrict__ ebuf,
                                                  int E, int B, int ept) {
    __shared__ int hist[512];
    __shared__ int cur[512];
    int blk = blockIdx.x, t = threadIdx.x;
    for (int i = t; i < B; i += 256) hist[i] = 0;
    __syncthreads();
    int start = blk * 256 * ept;
    for (int j = 0; j < ept; j++) {
        int e = start + j * 256 + t;
        if (e < E) atomicAdd(&hist[dst[e] >> 8], 1);
    }
    __syncthreads();
    for (int b = t; b < B; b += 256)
        cur[b] = b * CAP + atomicAdd(&btotal[b], hist[b]);
    __syncthreads();
    for (int j = 0; j < ept; j++) {
        int e = start + j * 256 + t;
        if (e < E) {
            int d = dst[e];
            int b = d >> 8;
            int pos = atomicAdd(&cur[b], 1);
            if (pos < (b + 1) * CAP)   // 23-sigma margin; clamp for safety
                ebuf[pos] = make_int2(src[e] | ((d & 255) << 24), __float_as_int(ew[e]));
        }
    }
}

// ---- per-bucket node grouping -> packed 4B CSR + offs + dinv + xp(fp16) ----
__global__ __launch_bounds__(256) void k_bucket_csr(const int2* __restrict__ ebuf,
                                                    const int* __restrict__ btotal,
                                                    unsigned int* __restrict__ csr,
                                                    unsigned int* __restrict__ offs,
                                                    float* __restrict__ dinv,
                                                    const float* __restrict__ x,
                                                    _Float16* __restrict__ xp,
                                                    int N) {
    __shared__ int ncnt[256];
    __shared__ int excl[256];
    __shared__ float wsum[256];
    int b = blockIdx.x, t = threadIdx.x;
    int base = b * CAP;
    int end = base + min(btotal[b], CAP);
    ncnt[t] = 0;
    wsum[t] = 0.0f;
    __syncthreads();
    for (int i = base + t; i < end; i += 256)
        atomicAdd(&ncnt[(unsigned)ebuf[i].x >> 24], 1);
    __syncthreads();
    int v = ncnt[t];
    excl[t] = v;
    __syncthreads();
#pragma unroll
    for (int o = 1; o < 256; o <<= 1) {
        int x2 = (t >= o) ? excl[t - o] : 0;
        __syncthreads();
        excl[t] += x2;
        __syncthreads();
    }
    int ex = excl[t] - v;                 // exclusive prefix within bucket
    int n = (b << 8) + t;
    if (n < N) offs[n] = (unsigned)(base + ex) | ((unsigned)v << 24);
    __syncthreads();
    ncnt[t] = base + ex;                  // reuse as per-node cursor
    __syncthreads();
    for (int i = base + t; i < end; i += 256) {
        int2 ent = ebuf[i];
        int node = (unsigned)ent.x >> 24;
        float w = __int_as_float(ent.y);
        int pos = atomicAdd(&ncnt[node], 1);
        csr[pos] = packent(ent.x & 0x00FFFFFF, w);
        atomicAdd(&wsum[node], w);
    }
    __syncthreads();
    if (n < N) {
        float dv = 1.0f / sqrtf(1.0f + wsum[t]);
        dinv[n] = dv;
        const float4* xr = (const float4*)(x + (long long)n * 16);
        half8* xw = (half8*)(xp + (long long)n * 16);
#pragma unroll
        for (int j = 0; j < 2; j++) {
            float4 a = xr[2 * j], c = xr[2 * j + 1];
            half8 hv;
            hv[0] = (_Float16)(a.x * dv); hv[1] = (_Float16)(a.y * dv);
            hv[2] = (_Float16)(a.z * dv); hv[3] = (_Float16)(a.w * dv);
            hv[4] = (_Float16)(c.x * dv); hv[5] = (_Float16)(c.y * dv);
            hv[6] = (_Float16)(c.z * dv); hv[7] = (_Float16)(c.w * dv);
            xw[j] = hv;
        }
    }
}

// ---- fused gather16 + 16->16 GEMM + silu: h1 = silu(y@W1+b1)*dinv (fp16 io) ----
// Edge-group eg owns a CONTIGUOUS quarter of the row, ILP8. Packed 4B csr.
__global__ __launch_bounds__(256) void k_gx1(const _Float16* __restrict__ h,
                                             const unsigned int* __restrict__ csr,
                                             const unsigned int* __restrict__ offs,
                                             const float* __restrict__ dinv,
                                             const float* __restrict__ W,
                                             const float* __restrict__ b,
                                             _Float16* __restrict__ out, int N) {
    __shared__ float Ws[16 * 16];
    __shared__ float bs[16];
    if (threadIdx.x < 256) Ws[threadIdx.x] = W[threadIdx.x];
    if (threadIdx.x < 16) bs[threadIdx.x] = b[threadIdx.x];
    __syncthreads();
    int n = blockIdx.x * 4 + (threadIdx.x >> 6);
    n = __builtin_amdgcn_readfirstlane(n);
    if (n >= N) return;
    int lane = threadIdx.x & 63;
    int d = lane & 15, eg = lane >> 4;
    unsigned op = offs[n];
    int p0 = op & 0x00FFFFFF;
    int len = op >> 24;
    int qs = p0 + ((len * eg) >> 2);
    int qe = p0 + ((len * (eg + 1)) >> 2);
    float acc = 0.0f;
    int p = qs;
    for (; p + 7 < qe; p += 8) {
        unsigned ee[8];
#pragma unroll
        for (int i = 0; i < 8; i++) ee[i] = csr[p + i];
        float vv[8];
#pragma unroll
        for (int i = 0; i < 8; i++) vv[i] = (float)h[psrc(ee[i]) * 16 + d];
#pragma unroll
        for (int i = 0; i < 8; i++) acc += pew(ee[i]) * vv[i];
    }
    if (p + 3 < qe) {
        unsigned e0 = csr[p], e1 = csr[p + 1], e2 = csr[p + 2], e3 = csr[p + 3];
        float v0 = (float)h[psrc(e0) * 16 + d], v1 = (float)h[psrc(e1) * 16 + d];
        float v2 = (float)h[psrc(e2) * 16 + d], v3 = (float)h[psrc(e3) * 16 + d];
        acc += pew(e0) * v0; acc += pew(e1) * v1;
        acc += pew(e2) * v2; acc += pew(e3) * v3;
        p += 4;
    }
    if (p + 1 < qe) {
        unsigned e0 = csr[p], e1 = csr[p + 1];
        acc += pew(e0) * (float)h[psrc(e0) * 16 + d];
        acc += pew(e1) * (float)h[psrc(e1) * 16 + d];
        p += 2;
    }
    if (p < qe) {
        unsigned e0 = csr[p];
        acc += pew(e0) * (float)h[psrc(e0) * 16 + d];
    }
    acc += __shfl_down(acc, 32, 64);
    acc += __shfl_down(acc, 16, 64);
    float dv = dinv[n];
    float yv = (acc + ((lane < 16) ? (float)h[n * 16 + lane] : 0.0f)) * dv;
    float o = bs[d];
#pragma unroll
    for (int k = 0; k < 16; k++) o += __shfl(yv, k, 64) * Ws[k * 16 + d];
    if (lane < 16) out[n * 16 + lane] = (_Float16)(silu_f(o) * dv);
}

// ---- fused gather16 + 16->64 GEMM + silu: h2 = silu(y@W2+b2)*dinv (fp16 io) ----
__global__ __launch_bounds__(256) void k_gx2(const _Float16* __restrict__ h,
                                             const unsigned int* __restrict__ csr,
                                             const unsigned int* __restrict__ offs,
                                             const float* __restrict__ dinv,
                                             const float* __restrict__ W,
                                             const float* __restrict__ b,
                                             _Float16* __restrict__ out, int N) {
    __shared__ float Ws[16 * 64];
    __shared__ float bs[64];
    for (int i = threadIdx.x; i < 16 * 64; i += 256) Ws[i] = W[i];
    if (threadIdx.x < 64) bs[threadIdx.x] = b[threadIdx.x];
    __syncthreads();
    int n = blockIdx.x * 4 + (threadIdx.x >> 6);
    n = __builtin_amdgcn_readfirstlane(n);
    if (n >= N) return;
    int lane = threadIdx.x & 63;
    int d = lane & 15, eg = lane >> 4;
    unsigned op = offs[n];
    int p0 = op & 0x00FFFFFF;
    int len = op >> 24;
    int qs = p0 + ((len * eg) >> 2);
    int qe = p0 + ((len * (eg + 1)) >> 2);
    float acc = 0.0f;
    int p = qs;
    for (; p + 7 < qe; p += 8) {
        unsigned ee[8];
#pragma unroll
        for (int i = 0; i < 8; i++) ee[i] = csr[p + i];
        float vv[8];
#pragma unroll
        for (int i = 0; i < 8; i++) vv[i] = (float)h[psrc(ee[i]) * 16 + d];
#pragma unroll
        for (int i = 0; i < 8; i++) acc += pew(ee[i]) * vv[i];
    }
    if (p + 3 < qe) {
        unsigned e0 = csr[p], e1 = csr[p + 1], e2 = csr[p + 2], e3 = csr[p + 3];
        float v0 = (float)h[psrc(e0) * 16 + d], v1 = (float)h[psrc(e1) * 16 + d];
        float v2 = (float)h[psrc(e2) * 16 + d], v3 = (float)h[psrc(e3) * 16 + d];
        acc += pew(e0) * v0; acc += pew(e1) * v1;
        acc += pew(e2) * v2; acc += pew(e3) * v3;
        p += 4;
    }
    if (p + 1 < qe) {
        unsigned e0 = csr[p], e1 = csr[p + 1];
        acc += pew(e0) * (float)h[psrc(e0) * 16 + d];
        acc += pew(e1) * (float)h[psrc(e1) * 16 + d];
        p += 2;
    }
    if (p < qe) {
        unsigned e0 = csr[p];
        acc += pew(e0) * (float)h[psrc(e0) * 16 + d];
    }
    acc += __shfl_down(acc, 32, 64);
    acc += __shfl_down(acc, 16, 64);
    float dv = dinv[n];
    float yv = (acc + ((lane < 16) ? (float)h[n * 16 + lane] : 0.0f)) * dv;
    float o = bs[lane];
#pragma unroll
    for (int k = 0; k < 16; k++) o += __shfl(yv, k, 64) * Ws[k * 64 + lane];
    out[(long long)n * 64 + lane] = (_Float16)(silu_f(o) * dv);
}

// ---- gather D=64 fp16 rows (128B = 1 line) + self term; fp16 y out ----
__global__ __launch_bounds__(256) void k_gather64(const _Float16* __restrict__ h,
                                                  const unsigned int* __restrict__ csr,
                                                  const unsigned int* __restrict__ offs,
                                                  const float* __restrict__ dinv,
                                                  _Float16* __restrict__ y, int N) {
    int n = blockIdx.x * 4 + (threadIdx.x >> 6);
    n = __builtin_amdgcn_readfirstlane(n);
    if (n >= N) return;
    int lane = threadIdx.x & 63;
    unsigned op = offs[n];
    const unsigned* row = csr + (op & 0x00FFFFFF);
    int len = op >> 24;
    float acc = 0.0f;
    int j = 0;
    for (; j + 7 < len; j += 8) {
        unsigned ee[8];
        float vv[8];
#pragma unroll
        for (int i = 0; i < 8; i++) ee[i] = row[j + i];
#pragma unroll
        for (int i = 0; i < 8; i++) vv[i] = (float)h[psrc(ee[i]) * 64 + lane];
#pragma unroll
        for (int i = 0; i < 8; i++) acc += pew(ee[i]) * vv[i];
    }
    if (j + 3 < len) {                     // ILP 4 tail
        unsigned e0 = row[j], e1 = row[j + 1], e2 = row[j + 2], e3 = row[j + 3];
        float v0 = (float)h[psrc(e0) * 64 + lane];
        float v1 = (float)h[psrc(e1) * 64 + lane];
        float v2 = (float)h[psrc(e2) * 64 + lane];
        float v3 = (float)h[psrc(e3) * 64 + lane];
        acc += pew(e0) * v0;
        acc += pew(e1) * v1;
        acc += pew(e2) * v2;
        acc += pew(e3) * v3;
        j += 4;
    }
    for (; j < len; j++) {
        unsigned e0 = row[j];
        acc += pew(e0) * (float)h[psrc(e0) * 64 + lane];
    }
    y[n * 64 + lane] = (_Float16)((acc + (float)h[n * 64 + lane]) * dinv[n]);
}

// ---- layer-3 via MFMA f16: GEMM [ce-cs,64]@[64,256] + bias + silu + pool ----
// Wave owns out-tiles wave*4..wave*4+3. W3 read as f32, converted to f16
// B-frags in registers (64KB L2-hot), reused across all node tiles. A-frags
// direct from global y (L1-hot). No LDS, no barriers.
// Frag layouts: A row=lane&15, k=8*(lane>>4)+j; B col=lane&15, same k;
// C/D col=lane&15, row=4*(lane>>4)+reg (m89-verified).
__global__ __launch_bounds__(256) void k_xform3pool(const _Float16* __restrict__ y,
                                                    const float* __restrict__ W,
                                                    const float* __restrict__ b,
                                                    const int* __restrict__ bounds,
                                                    float* __restrict__ partial,
                                                    int N) {
    int lane = threadIdx.x & 63;
    int wave = threadIdx.x >> 6;
    int g = blockIdx.x / POOL_C;
    int c = blockIdx.x % POOL_C;
    int s = bounds[g], e = bounds[g + 1];
    int len = e - s;
    int cs = s + (int)((long long)len * c / POOL_C);
    int ce = s + (int)((long long)len * (c + 1) / POOL_C);
    int lg = lane >> 4;        // lane-group (k-block for A/B, row-block for C)
    int lr = lane & 15;        // A row / B,C col

    half8 bf[4][2];            // [out-tile][kstep] W fragments, in registers
#pragma unroll
    for (int t = 0; t < 4; t++) {
        int col = (wave * 4 + t) * 16 + lr;
#pragma unroll
        for (int s2 = 0; s2 < 2; s2++) {
            half8 v;
#pragma unroll
            for (int j = 0; j < 8; j++)
                v[j] = (_Float16)W[(s2 * 32 + lg * 8 + j) * 256 + col];
            bf[t][s2] = v;
        }
    }
    float bias[4];
#pragma unroll
    for (int t = 0; t < 4; t++) bias[t] = b[(wave * 4 + t) * 16 + lr];

    float pacc[4] = {0.f, 0.f, 0.f, 0.f};

    for (int base = cs; base < ce; base += 16) {
        int node = base + lr;
        int cn = node < N ? node : N - 1;      // clamp addr; masked at pool
        const half8* arow = (const half8*)(y + (long long)cn * 64);
        half8 a0 = arow[lg];                   // k = 0..31, this group's 8
        half8 a1 = arow[4 + lg];               // k = 32..63
#pragma unroll
        for (int t = 0; t < 4; t++) {
            f32x4 acc = {0.f, 0.f, 0.f, 0.f};
            acc = __builtin_amdgcn_mfma_f32_16x16x32_f16(a0, bf[t][0], acc, 0, 0, 0);
            acc = __builtin_amdgcn_mfma_f32_16x16x32_f16(a1, bf[t][1], acc, 0, 0, 0);
#pragma unroll
            for (int r = 0; r < 4; r++) {
                int nrow = base + lg * 4 + r;  // C row -> node
                if (nrow < ce) pacc[t] += silu_f(acc[r] + bias[t]);
            }
        }
    }
    // reduce over the 4 row-groups: lanes sharing lr
#pragma unroll
    for (int t = 0; t < 4; t++) {
        pacc[t] += __shfl_xor(pacc[t], 16, 64);
        pacc[t] += __shfl_xor(pacc[t], 32, 64);
    }
    if (lane < 16) {
        float* pr = partial + (long long)blockIdx.x * 256 + wave * 64;
#pragma unroll
        for (int t = 0; t < 4; t++) pr[t * 16 + lane] = pacc[t];
    }
}

// ---- pool stage 2 + MLP ----
__global__ __launch_bounds__(256) void k_mlp(const float* __restrict__ partial,
                                             const int* __restrict__ bounds,
                                             const float* __restrict__ L1,
                                             const float* __restrict__ c1,
                                             const float* __restrict__ L2,
                                             const float* __restrict__ c2,
                                             const float* __restrict__ L3,
                                             const float* __restrict__ c3,
                                             float* __restrict__ out) {
    __shared__ float pooled[256];
    __shared__ float z1[128];
    __shared__ float z2[64];
    int g = blockIdx.x;
    int t = threadIdx.x;
    int cnt = bounds[g + 1] - bounds[g];
    float s = 0.0f;
    for (int c = 0; c < POOL_C; c++) s += partial[((long long)g * POOL_C + c) * 256 + t];
    pooled[t] = s / (float)(cnt > 0 ? cnt : 1);
    __syncthreads();
    if (t < 128) {
        float acc = c1[t];
        for (int k = 0; k < 256; k++) acc += pooled[k] * L1[k * 128 + t];
        z1[t] = silu_f(acc);
    }
    __syncthreads();
    if (t < 64) {
        float acc = c2[t];
        for (int k = 0; k < 128; k++) acc += z1[k] * L2[k * 64 + t];
        z2[t] = silu_f(acc);
    }
    __syncthreads();
    if (t < 3) {
        float acc = c3[t];
        for (int k = 0; k < 64; k++) acc += z2[k] * L3[k * 3 + t];
        out[g * 3 + t] = acc;
    }
}

extern "C" void kernel_launch(void* const* d_in, const int* in_sizes, int n_in,
                              void* d_out, int out_size, void* d_ws, size_t ws_size,
                              hipStream_t stream) {
    const float* x     = (const float*)d_in[0];
    const int*   ei    = (const int*)d_in[1];
    const float* ea    = (const float*)d_in[2];
    const int*   batch = (const int*)d_in[3];
    const float* W1 = (const float*)d_in[4];
    const float* b1 = (const float*)d_in[5];
    const float* W2 = (const float*)d_in[6];
    const float* b2 = (const float*)d_in[7];
    const float* W3 = (const float*)d_in[8];
    const float* b3 = (const float*)d_in[9];
    const float* L1 = (const float*)d_in[10];
    const float* c1 = (const float*)d_in[11];
    const float* L2 = (const float*)d_in[12];
    const float* c2 = (const float*)d_in[13];
    const float* L3 = (const float*)d_in[14];
    const float* c3 = (const float*)d_in[15];
    float* out = (float*)d_out;

    const int N = in_sizes[0] / 16;
    const int E = in_sizes[2];
    const int G = out_size / 3;
    const int* src = ei;
    const int* dst = ei + E;
    const int B = (N + 255) >> 8;               // buckets (<=512)
    const int ept = (E + NBH * 256 - 1) / (NBH * 256);

    char* ws = (char*)d_ws;
    size_t off = 0;
    auto alloc = [&](size_t bytes) -> void* {
        void* p = (void*)(ws + off);
        off += (bytes + 255) & ~(size_t)255;
        return p;
    };
    float*        dinv    = (float*)alloc((size_t)N * 4);
    unsigned int* offs    = (unsigned int*)alloc((size_t)N * 4);
    int*          btotal  = (int*)  alloc(512 * 4);
    int*          bounds  = (int*)  alloc((size_t)(G + 1) * 4);
    int2*         ebuf    = (int2*) alloc((size_t)B * CAP * 8);   // padded buckets
    unsigned int* csr     = (unsigned int*)alloc((size_t)B * CAP * 4); // packed CSR
    _Float16*     xp      = (_Float16*)alloc((size_t)N * 16 * 2);
    _Float16*     h1s     = (_Float16*)alloc((size_t)N * 16 * 2);
    _Float16*     h2s     = (_Float16*)alloc((size_t)N * 64 * 2);
    _Float16*     y64     = (_Float16*)alloc((size_t)N * 64 * 2);
    float*        partial = (float*)alloc((size_t)G * POOL_C * 256 * 4);
    (void)ws_size;

    // ---- init, then single-kernel bucket scatter + node grouping ----
    k_init<<<1, 512, 0, stream>>>(batch, bounds, btotal, N, G);
    k_bscatter<<<NBH, 256, 0, stream>>>(src, dst, ea, btotal, ebuf, E, B, ept);
    k_bucket_csr<<<B, 256, 0, stream>>>(ebuf, btotal, csr, offs, dinv, x, xp, N);

    // ---- layer 1 (fused gather+xform) ----
    k_gx1<<<(N + 3) / 4, 256, 0, stream>>>(xp, csr, offs, dinv, W1, b1, h1s, N);

    // ---- layer 2 (fused gather+xform) ----
    k_gx2<<<(N + 3) / 4, 256, 0, stream>>>(h1s, csr, offs, dinv, W2, b2, h2s, N);

    // ---- layer 3: gather fp16, then MFMA GEMM+silu+pool (h3 never written) ----
    k_gather64<<<(N + 3) / 4, 256, 0, stream>>>(h2s, csr, offs, dinv, y64, N);
    k_xform3pool<<<G * POOL_C, 256, 0, stream>>>(y64, W3, b3, bounds, partial, N);

    // ---- MLP head ----
    k_mlp<<<G, 256, 0, stream>>>(partial, bounds, L1, c1, L2, c2, L3, c3, out);
}

// Round 6
// 396.813 us; speedup vs baseline: 2.1839x; 1.0759x over previous
//
#include <hip/hip_runtime.h>
#include <math.h>

// ---------------------------------------------------------------------------
// GNN: 3x GCNConv(edge-weighted, self-loops) + SiLU, mean-pool, MLP.
// R1-R11: CSR-by-dst, fused gather+xform, two-stage pool, padded buckets. 540us
// R12: nt-hints REGRESSED (707). R13: revert (545.4).
// R14: fp16 feature storage xp/h1s/h2s. 545 -> 477us.
// R15: layer-3 as MFMA f16, W-frags in registers. 477 -> 433.6us.
// R16: NBH x4: occupancy 9->33% but bscatter UNCHANGED -> not latency-TLP.
// R17: global-atomic CSR build REGRESSED (k_count 279us). Revert.
// R18: packed 4B CSR (src17|ew-fp16): only -3us -> layer kernels not
//      csr-stream-bound. Keep (free). 430 -> 426.9us, absmax 1.9e-6.
// R19 (this round): bscatter theory = per-transaction occupancy: scattered
//      8B wave-stores = 64 line-requests each; bounded per-CU outstanding
//      budget x ~600cy fabric latency caps at ~7.7cy/edge with all pipes
//      idle (also explains R17: atomics = same mechanism). Fix: block-level
//      counting sort in LDS (hist -> pair-scan prefix -> LDS-sorted sbuf ->
//      in-order writeout). Consecutive lanes write consecutive addresses
//      (~64B runs) -> ~8x fewer store transactions. ebuf format unchanged.
//      Predict bscatter 81 -> ~35us, WRITE_SIZE 90 -> ~30MB, total ~385us.
// ---------------------------------------------------------------------------

#define EPT 13        // edges per thread in bscatter (compile-time reg array)
#define SLICE (256 * EPT)
#define POOL_C 8      // chunks per graph for fused GEMM+pool (512 blocks = 2/CU)
#define CAP 10240     // padded bucket capacity (mean 8184, sigma~90)

typedef _Float16 half8 __attribute__((ext_vector_type(8)));
typedef float f32x4 __attribute__((ext_vector_type(4)));

__device__ __forceinline__ float silu_f(float v) { return v / (1.0f + expf(-v)); }

// ---- packed CSR entry helpers: u = (src<<15) | (fp16(ew) & 0x7FFF) ----
__device__ __forceinline__ int psrc(unsigned u) { return (int)(u >> 15); }
__device__ __forceinline__ float pew(unsigned u) {
    unsigned short hs = (unsigned short)(u & 0x7FFFu);
    _Float16 hv;
    __builtin_memcpy(&hv, &hs, 2);
    return (float)hv;
}
__device__ __forceinline__ unsigned packent(int src, float w) {
    _Float16 hw = (_Float16)w;
    unsigned short hb;
    __builtin_memcpy(&hb, &hw, 2);
    return ((unsigned)src << 15) | (unsigned)(hb & 0x7FFFu);
}

// ---- init: zero bucket cursors + graph boundaries (one tiny block) ----
__global__ void k_init(const int* __restrict__ batch, int* __restrict__ bounds,
                       int* __restrict__ btotal, int N, int G) {
    int t = threadIdx.x;
    btotal[t] = 0;                     // 512 threads, 512 ints
    if (t > G) return;
    if (t == G) { bounds[G] = N; return; }
    int lo = 0, hi = N;
    while (lo < hi) { int m = (lo + hi) >> 1; if (batch[m] < t) lo = m + 1; else hi = m; }
    bounds[t] = lo;
}

// ---- count + reserve + LDS counting-sort + coalesced chunk writeout ----
__global__ __launch_bounds__(256) void k_bscatter(const int* __restrict__ src,
                                                  const int* __restrict__ dst,
                                                  const float* __restrict__ ew,
                                                  int* __restrict__ btotal,
                                                  int2* __restrict__ ebuf,
                                                  int E, int B) {
    __shared__ int hist[512];
    __shared__ int pscan[256];
    __shared__ int excl[512];
    __shared__ int hcur[512];
    __shared__ int delta[512];
    __shared__ int2 sbuf[SLICE];           // 26.6KB block-sorted edges
    __shared__ unsigned short bbk[SLICE];  // 6.7KB bucket of sorted entry
    int blk = blockIdx.x, t = threadIdx.x;
    int start = blk * SLICE;
    int m = E - start;
    if (m > SLICE) m = SLICE;
    if (m < 0) m = 0;

    for (int i = t; i < 512; i += 256) hist[i] = 0;
    __syncthreads();

    // pass A: histogram; stage dst in registers
    int dreg[EPT];
#pragma unroll
    for (int j = 0; j < EPT; j++) {
        int e = start + j * 256 + t;
        dreg[j] = (e < E) ? dst[e] : -1;
        if (dreg[j] >= 0) atomicAdd(&hist[dreg[j] >> 8], 1);
    }
    __syncthreads();

    // pairwise exclusive scan of hist[0..511] with 256 threads
    int h0 = hist[2 * t], h1 = hist[2 * t + 1];
    pscan[t] = h0 + h1;
    __syncthreads();
#pragma unroll
    for (int o = 1; o < 256; o <<= 1) {
        int x2 = (t >= o) ? pscan[t - o] : 0;
        __syncthreads();
        pscan[t] += x2;
        __syncthreads();
    }
    int pex = pscan[t] - (h0 + h1);        // exclusive over pairs
    excl[2 * t] = pex;
    excl[2 * t + 1] = pex + h0;
    hcur[2 * t] = pex;
    hcur[2 * t + 1] = pex + h0;
    __syncthreads();

    // reserve global chunks; delta[b] maps local sorted idx -> global pos
    for (int b = t; b < 512; b += 256) {
        int cnt = hist[b];
        int gb = b * CAP;
        if (b < B && cnt > 0) gb += atomicAdd(&btotal[b], cnt);
        delta[b] = gb - excl[b];
    }
    __syncthreads();

    // pass B: scatter into LDS-sorted buffer (cheap LDS traffic)
#pragma unroll
    for (int j = 0; j < EPT; j++) {
        int e = start + j * 256 + t;
        if (e < E) {
            int d = dreg[j];
            int b = d >> 8;
            int pos = atomicAdd(&hcur[b], 1);
            sbuf[pos] = make_int2(src[e] | ((d & 255) << 24), __float_as_int(ew[e]));
            bbk[pos] = (unsigned short)b;
        }
    }
    __syncthreads();

    // pass C: in-order writeout -> consecutive lanes hit consecutive addrs
    for (int i = t; i < m; i += 256) {
        int b = bbk[i];
        int gpos = delta[b] + i;
        if (gpos < (b + 1) * CAP)          // 23-sigma margin; clamp for safety
            ebuf[gpos] = sbuf[i];
    }
}

// ---- per-bucket node grouping -> packed 4B CSR + offs + dinv + xp(fp16) ----
__global__ __launch_bounds__(256) void k_bucket_csr(const int2* __restrict__ ebuf,
                                                    const int* __restrict__ btotal,
                                                    unsigned int* __restrict__ csr,
                                                    unsigned int* __restrict__ offs,
                                                    float* __restrict__ dinv,
                                                    const float* __restrict__ x,
                                                    _Float16* __restrict__ xp,
                                                    int N) {
    __shared__ int ncnt[256];
    __shared__ int excl[256];
    __shared__ float wsum[256];
    int b = blockIdx.x, t = threadIdx.x;
    int base = b * CAP;
    int end = base + min(btotal[b], CAP);
    ncnt[t] = 0;
    wsum[t] = 0.0f;
    __syncthreads();
    for (int i = base + t; i < end; i += 256)
        atomicAdd(&ncnt[(unsigned)ebuf[i].x >> 24], 1);
    __syncthreads();
    int v = ncnt[t];
    excl[t] = v;
    __syncthreads();
#pragma unroll
    for (int o = 1; o < 256; o <<= 1) {
        int x2 = (t >= o) ? excl[t - o] : 0;
        __syncthreads();
        excl[t] += x2;
        __syncthreads();
    }
    int ex = excl[t] - v;                 // exclusive prefix within bucket
    int n = (b << 8) + t;
    if (n < N) offs[n] = (unsigned)(base + ex) | ((unsigned)v << 24);
    __syncthreads();
    ncnt[t] = base + ex;                  // reuse as per-node cursor
    __syncthreads();
    for (int i = base + t; i < end; i += 256) {
        int2 ent = ebuf[i];
        int node = (unsigned)ent.x >> 24;
        float w = __int_as_float(ent.y);
        int pos = atomicAdd(&ncnt[node], 1);
        csr[pos] = packent(ent.x & 0x00FFFFFF, w);
        atomicAdd(&wsum[node], w);
    }
    __syncthreads();
    if (n < N) {
        float dv = 1.0f / sqrtf(1.0f + wsum[t]);
        dinv[n] = dv;
        const float4* xr = (const float4*)(x + (long long)n * 16);
        half8* xw = (half8*)(xp + (long long)n * 16);
#pragma unroll
        for (int j = 0; j < 2; j++) {
            float4 a = xr[2 * j], c = xr[2 * j + 1];
            half8 hv;
            hv[0] = (_Float16)(a.x * dv); hv[1] = (_Float16)(a.y * dv);
            hv[2] = (_Float16)(a.z * dv); hv[3] = (_Float16)(a.w * dv);
            hv[4] = (_Float16)(c.x * dv); hv[5] = (_Float16)(c.y * dv);
            hv[6] = (_Float16)(c.z * dv); hv[7] = (_Float16)(c.w * dv);
            xw[j] = hv;
        }
    }
}

// ---- fused gather16 + 16->16 GEMM + silu: h1 = silu(y@W1+b1)*dinv (fp16 io) ----
// Edge-group eg owns a CONTIGUOUS quarter of the row, ILP8. Packed 4B csr.
__global__ __launch_bounds__(256) void k_gx1(const _Float16* __restrict__ h,
                                             const unsigned int* __restrict__ csr,
                                             const unsigned int* __restrict__ offs,
                                             const float* __restrict__ dinv,
                                             const float* __restrict__ W,
                                             const float* __restrict__ b,
                                             _Float16* __restrict__ out, int N) {
    __shared__ float Ws[16 * 16];
    __shared__ float bs[16];
    if (threadIdx.x < 256) Ws[threadIdx.x] = W[threadIdx.x];
    if (threadIdx.x < 16) bs[threadIdx.x] = b[threadIdx.x];
    __syncthreads();
    int n = blockIdx.x * 4 + (threadIdx.x >> 6);
    n = __builtin_amdgcn_readfirstlane(n);
    if (n >= N) return;
    int lane = threadIdx.x & 63;
    int d = lane & 15, eg = lane >> 4;
    unsigned op = offs[n];
    int p0 = op & 0x00FFFFFF;
    int len = op >> 24;
    int qs = p0 + ((len * eg) >> 2);
    int qe = p0 + ((len * (eg + 1)) >> 2);
    float acc = 0.0f;
    int p = qs;
    for (; p + 7 < qe; p += 8) {
        unsigned ee[8];
#pragma unroll
        for (int i = 0; i < 8; i++) ee[i] = csr[p + i];
        float vv[8];
#pragma unroll
        for (int i = 0; i < 8; i++) vv[i] = (float)h[psrc(ee[i]) * 16 + d];
#pragma unroll
        for (int i = 0; i < 8; i++) acc += pew(ee[i]) * vv[i];
    }
    if (p + 3 < qe) {
        unsigned e0 = csr[p], e1 = csr[p + 1], e2 = csr[p + 2], e3 = csr[p + 3];
        float v0 = (float)h[psrc(e0) * 16 + d], v1 = (float)h[psrc(e1) * 16 + d];
        float v2 = (float)h[psrc(e2) * 16 + d], v3 = (float)h[psrc(e3) * 16 + d];
        acc += pew(e0) * v0; acc += pew(e1) * v1;
        acc += pew(e2) * v2; acc += pew(e3) * v3;
        p += 4;
    }
    if (p + 1 < qe) {
        unsigned e0 = csr[p], e1 = csr[p + 1];
        acc += pew(e0) * (float)h[psrc(e0) * 16 + d];
        acc += pew(e1) * (float)h[psrc(e1) * 16 + d];
        p += 2;
    }
    if (p < qe) {
        unsigned e0 = csr[p];
        acc += pew(e0) * (float)h[psrc(e0) * 16 + d];
    }
    acc += __shfl_down(acc, 32, 64);
    acc += __shfl_down(acc, 16, 64);
    float dv = dinv[n];
    float yv = (acc + ((lane < 16) ? (float)h[n * 16 + lane] : 0.0f)) * dv;
    float o = bs[d];
#pragma unroll
    for (int k = 0; k < 16; k++) o += __shfl(yv, k, 64) * Ws[k * 16 + d];
    if (lane < 16) out[n * 16 + lane] = (_Float16)(silu_f(o) * dv);
}

// ---- fused gather16 + 16->64 GEMM + silu: h2 = silu(y@W2+b2)*dinv (fp16 io) ----
__global__ __launch_bounds__(256) void k_gx2(const _Float16* __restrict__ h,
                                             const unsigned int* __restrict__ csr,
                                             const unsigned int* __restrict__ offs,
                                             const float* __restrict__ dinv,
                                             const float* __restrict__ W,
                                             const float* __restrict__ b,
                                             _Float16* __restrict__ out, int N) {
    __shared__ float Ws[16 * 64];
    __shared__ float bs[64];
    for (int i = threadIdx.x; i < 16 * 64; i += 256) Ws[i] = W[i];
    if (threadIdx.x < 64) bs[threadIdx.x] = b[threadIdx.x];
    __syncthreads();
    int n = blockIdx.x * 4 + (threadIdx.x >> 6);
    n = __builtin_amdgcn_readfirstlane(n);
    if (n >= N) return;
    int lane = threadIdx.x & 63;
    int d = lane & 15, eg = lane >> 4;
    unsigned op = offs[n];
    int p0 = op & 0x00FFFFFF;
    int len = op >> 24;
    int qs = p0 + ((len * eg) >> 2);
    int qe = p0 + ((len * (eg + 1)) >> 2);
    float acc = 0.0f;
    int p = qs;
    for (; p + 7 < qe; p += 8) {
        unsigned ee[8];
#pragma unroll
        for (int i = 0; i < 8; i++) ee[i] = csr[p + i];
        float vv[8];
#pragma unroll
        for (int i = 0; i < 8; i++) vv[i] = (float)h[psrc(ee[i]) * 16 + d];
#pragma unroll
        for (int i = 0; i < 8; i++) acc += pew(ee[i]) * vv[i];
    }
    if (p + 3 < qe) {
        unsigned e0 = csr[p], e1 = csr[p + 1], e2 = csr[p + 2], e3 = csr[p + 3];
        float v0 = (float)h[psrc(e0) * 16 + d], v1 = (float)h[psrc(e1) * 16 + d];
        float v2 = (float)h[psrc(e2) * 16 + d], v3 = (float)h[psrc(e3) * 16 + d];
        acc += pew(e0) * v0; acc += pew(e1) * v1;
        acc += pew(e2) * v2; acc += pew(e3) * v3;
        p += 4;
    }
    if (p + 1 < qe) {
        unsigned e0 = csr[p], e1 = csr[p + 1];
        acc += pew(e0) * (float)h[psrc(e0) * 16 + d];
        acc += pew(e1) * (float)h[psrc(e1) * 16 + d];
        p += 2;
    }
    if (p < qe) {
        unsigned e0 = csr[p];
        acc += pew(e0) * (float)h[psrc(e0) * 16 + d];
    }
    acc += __shfl_down(acc, 32, 64);
    acc += __shfl_down(acc, 16, 64);
    float dv = dinv[n];
    float yv = (acc + ((lane < 16) ? (float)h[n * 16 + lane] : 0.0f)) * dv;
    float o = bs[lane];
#pragma unroll
    for (int k = 0; k < 16; k++) o += __shfl(yv, k, 64) * Ws[k * 64 + lane];
    out[(long long)n * 64 + lane] = (_Float16)(silu_f(o) * dv);
}

// ---- gather D=64 fp16 rows (128B = 1 line) + self term; fp16 y out ----
__global__ __launch_bounds__(256) void k_gather64(const _Float16* __restrict__ h,
                                                  const unsigned int* __restrict__ csr,
                                                  const unsigned int* __restrict__ offs,
                                                  const float* __restrict__ dinv,
                                                  _Float16* __restrict__ y, int N) {
    int n = blockIdx.x * 4 + (threadIdx.x >> 6);
    n = __builtin_amdgcn_readfirstlane(n);
    if (n >= N) return;
    int lane = threadIdx.x & 63;
    unsigned op = offs[n];
    const unsigned* row = csr + (op & 0x00FFFFFF);
    int len = op >> 24;
    float acc = 0.0f;
    int j = 0;
    for (; j + 7 < len; j += 8) {
        unsigned ee[8];
        float vv[8];
#pragma unroll
        for (int i = 0; i < 8; i++) ee[i] = row[j + i];
#pragma unroll
        for (int i = 0; i < 8; i++) vv[i] = (float)h[psrc(ee[i]) * 64 + lane];
#pragma unroll
        for (int i = 0; i < 8; i++) acc += pew(ee[i]) * vv[i];
    }
    if (j + 3 < len) {                     // ILP 4 tail
        unsigned e0 = row[j], e1 = row[j + 1], e2 = row[j + 2], e3 = row[j + 3];
        float v0 = (float)h[psrc(e0) * 64 + lane];
        float v1 = (float)h[psrc(e1) * 64 + lane];
        float v2 = (float)h[psrc(e2) * 64 + lane];
        float v3 = (float)h[psrc(e3) * 64 + lane];
        acc += pew(e0) * v0;
        acc += pew(e1) * v1;
        acc += pew(e2) * v2;
        acc += pew(e3) * v3;
        j += 4;
    }
    for (; j < len; j++) {
        unsigned e0 = row[j];
        acc += pew(e0) * (float)h[psrc(e0) * 64 + lane];
    }
    y[n * 64 + lane] = (_Float16)((acc + (float)h[n * 64 + lane]) * dinv[n]);
}

// ---- layer-3 via MFMA f16: GEMM [ce-cs,64]@[64,256] + bias + silu + pool ----
__global__ __launch_bounds__(256) void k_xform3pool(const _Float16* __restrict__ y,
                                                    const float* __restrict__ W,
                                                    const float* __restrict__ b,
                                                    const int* __restrict__ bounds,
                                                    float* __restrict__ partial,
                                                    int N) {
    int lane = threadIdx.x & 63;
    int wave = threadIdx.x >> 6;
    int g = blockIdx.x / POOL_C;
    int c = blockIdx.x % POOL_C;
    int s = bounds[g], e = bounds[g + 1];
    int len = e - s;
    int cs = s + (int)((long long)len * c / POOL_C);
    int ce = s + (int)((long long)len * (c + 1) / POOL_C);
    int lg = lane >> 4;        // lane-group (k-block for A/B, row-block for C)
    int lr = lane & 15;        // A row / B,C col

    half8 bf[4][2];            // [out-tile][kstep] W fragments, in registers
#pragma unroll
    for (int t = 0; t < 4; t++) {
        int col = (wave * 4 + t) * 16 + lr;
#pragma unroll
        for (int s2 = 0; s2 < 2; s2++) {
            half8 v;
#pragma unroll
            for (int j = 0; j < 8; j++)
                v[j] = (_Float16)W[(s2 * 32 + lg * 8 + j) * 256 + col];
            bf[t][s2] = v;
        }
    }
    float bias[4];
#pragma unroll
    for (int t = 0; t < 4; t++) bias[t] = b[(wave * 4 + t) * 16 + lr];

    float pacc[4] = {0.f, 0.f, 0.f, 0.f};

    for (int base = cs; base < ce; base += 16) {
        int node = base + lr;
        int cn = node < N ? node : N - 1;      // clamp addr; masked at pool
        const half8* arow = (const half8*)(y + (long long)cn * 64);
        half8 a0 = arow[lg];                   // k = 0..31, this group's 8
        half8 a1 = arow[4 + lg];               // k = 32..63
#pragma unroll
        for (int t = 0; t < 4; t++) {
            f32x4 acc = {0.f, 0.f, 0.f, 0.f};
            acc = __builtin_amdgcn_mfma_f32_16x16x32_f16(a0, bf[t][0], acc, 0, 0, 0);
            acc = __builtin_amdgcn_mfma_f32_16x16x32_f16(a1, bf[t][1], acc, 0, 0, 0);
#pragma unroll
            for (int r = 0; r < 4; r++) {
                int nrow = base + lg * 4 + r;  // C row -> node
                if (nrow < ce) pacc[t] += silu_f(acc[r] + bias[t]);
            }
        }
    }
    // reduce over the 4 row-groups: lanes sharing lr
#pragma unroll
    for (int t = 0; t < 4; t++) {
        pacc[t] += __shfl_xor(pacc[t], 16, 64);
        pacc[t] += __shfl_xor(pacc[t], 32, 64);
    }
    if (lane < 16) {
        float* pr = partial + (long long)blockIdx.x * 256 + wave * 64;
#pragma unroll
        for (int t = 0; t < 4; t++) pr[t * 16 + lane] = pacc[t];
    }
}

// ---- pool stage 2 + MLP ----
__global__ __launch_bounds__(256) void k_mlp(const float* __restrict__ partial,
                                             const int* __restrict__ bounds,
                                             const float* __restrict__ L1,
                                             const float* __restrict__ c1,
                                             const float* __restrict__ L2,
                                             const float* __restrict__ c2,
                                             const float* __restrict__ L3,
                                             const float* __restrict__ c3,
                                             float* __restrict__ out) {
    __shared__ float pooled[256];
    __shared__ float z1[128];
    __shared__ float z2[64];
    int g = blockIdx.x;
    int t = threadIdx.x;
    int cnt = bounds[g + 1] - bounds[g];
    float s = 0.0f;
    for (int c = 0; c < POOL_C; c++) s += partial[((long long)g * POOL_C + c) * 256 + t];
    pooled[t] = s / (float)(cnt > 0 ? cnt : 1);
    __syncthreads();
    if (t < 128) {
        float acc = c1[t];
        for (int k = 0; k < 256; k++) acc += pooled[k] * L1[k * 128 + t];
        z1[t] = silu_f(acc);
    }
    __syncthreads();
    if (t < 64) {
        float acc = c2[t];
        for (int k = 0; k < 128; k++) acc += z1[k] * L2[k * 64 + t];
        z2[t] = silu_f(acc);
    }
    __syncthreads();
    if (t < 3) {
        float acc = c3[t];
        for (int k = 0; k < 64; k++) acc += z2[k] * L3[k * 3 + t];
        out[g * 3 + t] = acc;
    }
}

extern "C" void kernel_launch(void* const* d_in, const int* in_sizes, int n_in,
                              void* d_out, int out_size, void* d_ws, size_t ws_size,
                              hipStream_t stream) {
    const float* x     = (const float*)d_in[0];
    const int*   ei    = (const int*)d_in[1];
    const float* ea    = (const float*)d_in[2];
    const int*   batch = (const int*)d_in[3];
    const float* W1 = (const float*)d_in[4];
    const float* b1 = (const float*)d_in[5];
    const float* W2 = (const float*)d_in[6];
    const float* b2 = (const float*)d_in[7];
    const float* W3 = (const float*)d_in[8];
    const float* b3 = (const float*)d_in[9];
    const float* L1 = (const float*)d_in[10];
    const float* c1 = (const float*)d_in[11];
    const float* L2 = (const float*)d_in[12];
    const float* c2 = (const float*)d_in[13];
    const float* L3 = (const float*)d_in[14];
    const float* c3 = (const float*)d_in[15];
    float* out = (float*)d_out;

    const int N = in_sizes[0] / 16;
    const int E = in_sizes[2];
    const int G = out_size / 3;
    const int* src = ei;
    const int* dst = ei + E;
    const int B = (N + 255) >> 8;               // buckets (<=512)
    const int NBH = (E + SLICE - 1) / SLICE;    // one 3328-edge slice per block

    char* ws = (char*)d_ws;
    size_t off = 0;
    auto alloc = [&](size_t bytes) -> void* {
        void* p = (void*)(ws + off);
        off += (bytes + 255) & ~(size_t)255;
        return p;
    };
    float*        dinv    = (float*)alloc((size_t)N * 4);
    unsigned int* offs    = (unsigned int*)alloc((size_t)N * 4);
    int*          btotal  = (int*)  alloc(512 * 4);
    int*          bounds  = (int*)  alloc((size_t)(G + 1) * 4);
    int2*         ebuf    = (int2*) alloc((size_t)B * CAP * 8);   // padded buckets
    unsigned int* csr     = (unsigned int*)alloc((size_t)B * CAP * 4); // packed CSR
    _Float16*     xp      = (_Float16*)alloc((size_t)N * 16 * 2);
    _Float16*     h1s     = (_Float16*)alloc((size_t)N * 16 * 2);
    _Float16*     h2s     = (_Float16*)alloc((size_t)N * 64 * 2);
    _Float16*     y64     = (_Float16*)alloc((size_t)N * 64 * 2);
    float*        partial = (float*)alloc((size_t)G * POOL_C * 256 * 4);
    (void)ws_size;

    // ---- init, then single-kernel bucket scatter + node grouping ----
    k_init<<<1, 512, 0, stream>>>(batch, bounds, btotal, N, G);
    k_bscatter<<<NBH, 256, 0, stream>>>(src, dst, ea, btotal, ebuf, E, B);
    k_bucket_csr<<<B, 256, 0, stream>>>(ebuf, btotal, csr, offs, dinv, x, xp, N);

    // ---- layer 1 (fused gather+xform) ----
    k_gx1<<<(N + 3) / 4, 256, 0, stream>>>(xp, csr, offs, dinv, W1, b1, h1s, N);

    // ---- layer 2 (fused gather+xform) ----
    k_gx2<<<(N + 3) / 4, 256, 0, stream>>>(h1s, csr, offs, dinv, W2, b2, h2s, N);

    // ---- layer 3: gather fp16, then MFMA GEMM+silu+pool (h3 never written) ----
    k_gather64<<<(N + 3) / 4, 256, 0, stream>>>(h2s, csr, offs, dinv, y64, N);
    k_xform3pool<<<G * POOL_C, 256, 0, stream>>>(y64, W3, b3, bounds, partial, N);

    // ---- MLP head ----
    k_mlp<<<G, 256, 0, stream>>>(partial, bounds, L1, c1, L2, c2, L3, c3, out);
}

// Round 7
// 387.013 us; speedup vs baseline: 2.2392x; 1.0253x over previous
//
#include <hip/hip_runtime.h>
#include <math.h>

// ---------------------------------------------------------------------------
// GNN: 3x GCNConv(edge-weighted, self-loops) + SiLU, mean-pool, MLP.
// R1-R11: CSR-by-dst, fused gather+xform, two-stage pool, padded buckets. 540us
// R12: nt-hints REGRESSED (707). R13: revert (545.4).
// R14: fp16 feature storage xp/h1s/h2s. 545 -> 477us.
// R15: layer-3 as MFMA f16, W-frags in registers. 477 -> 433.6us.
// R16: NBH x4: occupancy 9->33% but bscatter UNCHANGED -> not latency-TLP.
// R17: global-atomic CSR build REGRESSED (k_count 279us). Revert.
// R18: packed 4B CSR (src17|ew-fp16): only -3us. Keep (free). 426.9us.
// R19: bscatter LDS counting-sort -> coalesced writeout: 81 -> 63us,
//      WRITE 90 -> 34MB (transaction-merge theory confirmed). 396.8us.
// R20 (this round): k_gather64 latency-ILP bound (11.9 cyc/edge, VALU 45%,
//      HBM 46%, occ 70% -- nothing saturated; 8 edges in flight/wave).
//      2 edges per wave-step: lane loads fp16x2 (4B), lanes 0-31 = edge j,
//      lanes 32-63 = edge j+1; entries via uniform scalar loads + cndmask;
//      shfl_xor(32) combine; lanes 0-31 write 4B. Halves per-edge wave
//      instrs, doubles in-flight edges to 16. Predict gather64 62 -> ~40us,
//      total ~375us. If >=55us: latency theory wrong, it's a fabric floor.
// ---------------------------------------------------------------------------

#define EPT 13        // edges per thread in bscatter (compile-time reg array)
#define SLICE (256 * EPT)
#define POOL_C 8      // chunks per graph for fused GEMM+pool (512 blocks = 2/CU)
#define CAP 10240     // padded bucket capacity (mean 8184, sigma~90)

typedef _Float16 half8 __attribute__((ext_vector_type(8)));
typedef _Float16 half2v __attribute__((ext_vector_type(2)));
typedef float f32x4 __attribute__((ext_vector_type(4)));

__device__ __forceinline__ float silu_f(float v) { return v / (1.0f + expf(-v)); }

// ---- packed CSR entry helpers: u = (src<<15) | (fp16(ew) & 0x7FFF) ----
__device__ __forceinline__ int psrc(unsigned u) { return (int)(u >> 15); }
__device__ __forceinline__ float pew(unsigned u) {
    unsigned short hs = (unsigned short)(u & 0x7FFFu);
    _Float16 hv;
    __builtin_memcpy(&hv, &hs, 2);
    return (float)hv;
}
__device__ __forceinline__ unsigned packent(int src, float w) {
    _Float16 hw = (_Float16)w;
    unsigned short hb;
    __builtin_memcpy(&hb, &hw, 2);
    return ((unsigned)src << 15) | (unsigned)(hb & 0x7FFFu);
}

// ---- init: zero bucket cursors + graph boundaries (one tiny block) ----
__global__ void k_init(const int* __restrict__ batch, int* __restrict__ bounds,
                       int* __restrict__ btotal, int N, int G) {
    int t = threadIdx.x;
    btotal[t] = 0;                     // 512 threads, 512 ints
    if (t > G) return;
    if (t == G) { bounds[G] = N; return; }
    int lo = 0, hi = N;
    while (lo < hi) { int m = (lo + hi) >> 1; if (batch[m] < t) lo = m + 1; else hi = m; }
    bounds[t] = lo;
}

// ---- count + reserve + LDS counting-sort + coalesced chunk writeout ----
__global__ __launch_bounds__(256) void k_bscatter(const int* __restrict__ src,
                                                  const int* __restrict__ dst,
                                                  const float* __restrict__ ew,
                                                  int* __restrict__ btotal,
                                                  int2* __restrict__ ebuf,
                                                  int E, int B) {
    __shared__ int hist[512];
    __shared__ int pscan[256];
    __shared__ int excl[512];
    __shared__ int hcur[512];
    __shared__ int delta[512];
    __shared__ int2 sbuf[SLICE];           // 26.6KB block-sorted edges
    __shared__ unsigned short bbk[SLICE];  // 6.7KB bucket of sorted entry
    int blk = blockIdx.x, t = threadIdx.x;
    int start = blk * SLICE;
    int m = E - start;
    if (m > SLICE) m = SLICE;
    if (m < 0) m = 0;

    for (int i = t; i < 512; i += 256) hist[i] = 0;
    __syncthreads();

    // pass A: histogram; stage dst in registers
    int dreg[EPT];
#pragma unroll
    for (int j = 0; j < EPT; j++) {
        int e = start + j * 256 + t;
        dreg[j] = (e < E) ? dst[e] : -1;
        if (dreg[j] >= 0) atomicAdd(&hist[dreg[j] >> 8], 1);
    }
    __syncthreads();

    // pairwise exclusive scan of hist[0..511] with 256 threads
    int h0 = hist[2 * t], h1 = hist[2 * t + 1];
    pscan[t] = h0 + h1;
    __syncthreads();
#pragma unroll
    for (int o = 1; o < 256; o <<= 1) {
        int x2 = (t >= o) ? pscan[t - o] : 0;
        __syncthreads();
        pscan[t] += x2;
        __syncthreads();
    }
    int pex = pscan[t] - (h0 + h1);        // exclusive over pairs
    excl[2 * t] = pex;
    excl[2 * t + 1] = pex + h0;
    hcur[2 * t] = pex;
    hcur[2 * t + 1] = pex + h0;
    __syncthreads();

    // reserve global chunks; delta[b] maps local sorted idx -> global pos
    for (int b = t; b < 512; b += 256) {
        int cnt = hist[b];
        int gb = b * CAP;
        if (b < B && cnt > 0) gb += atomicAdd(&btotal[b], cnt);
        delta[b] = gb - excl[b];
    }
    __syncthreads();

    // pass B: scatter into LDS-sorted buffer (cheap LDS traffic)
#pragma unroll
    for (int j = 0; j < EPT; j++) {
        int e = start + j * 256 + t;
        if (e < E) {
            int d = dreg[j];
            int b = d >> 8;
            int pos = atomicAdd(&hcur[b], 1);
            sbuf[pos] = make_int2(src[e] | ((d & 255) << 24), __float_as_int(ew[e]));
            bbk[pos] = (unsigned short)b;
        }
    }
    __syncthreads();

    // pass C: in-order writeout -> consecutive lanes hit consecutive addrs
    for (int i = t; i < m; i += 256) {
        int b = bbk[i];
        int gpos = delta[b] + i;
        if (gpos < (b + 1) * CAP)          // 23-sigma margin; clamp for safety
            ebuf[gpos] = sbuf[i];
    }
}

// ---- per-bucket node grouping -> packed 4B CSR + offs + dinv + xp(fp16) ----
__global__ __launch_bounds__(256) void k_bucket_csr(const int2* __restrict__ ebuf,
                                                    const int* __restrict__ btotal,
                                                    unsigned int* __restrict__ csr,
                                                    unsigned int* __restrict__ offs,
                                                    float* __restrict__ dinv,
                                                    const float* __restrict__ x,
                                                    _Float16* __restrict__ xp,
                                                    int N) {
    __shared__ int ncnt[256];
    __shared__ int excl[256];
    __shared__ float wsum[256];
    int b = blockIdx.x, t = threadIdx.x;
    int base = b * CAP;
    int end = base + min(btotal[b], CAP);
    ncnt[t] = 0;
    wsum[t] = 0.0f;
    __syncthreads();
    for (int i = base + t; i < end; i += 256)
        atomicAdd(&ncnt[(unsigned)ebuf[i].x >> 24], 1);
    __syncthreads();
    int v = ncnt[t];
    excl[t] = v;
    __syncthreads();
#pragma unroll
    for (int o = 1; o < 256; o <<= 1) {
        int x2 = (t >= o) ? excl[t - o] : 0;
        __syncthreads();
        excl[t] += x2;
        __syncthreads();
    }
    int ex = excl[t] - v;                 // exclusive prefix within bucket
    int n = (b << 8) + t;
    if (n < N) offs[n] = (unsigned)(base + ex) | ((unsigned)v << 24);
    __syncthreads();
    ncnt[t] = base + ex;                  // reuse as per-node cursor
    __syncthreads();
    for (int i = base + t; i < end; i += 256) {
        int2 ent = ebuf[i];
        int node = (unsigned)ent.x >> 24;
        float w = __int_as_float(ent.y);
        int pos = atomicAdd(&ncnt[node], 1);
        csr[pos] = packent(ent.x & 0x00FFFFFF, w);
        atomicAdd(&wsum[node], w);
    }
    __syncthreads();
    if (n < N) {
        float dv = 1.0f / sqrtf(1.0f + wsum[t]);
        dinv[n] = dv;
        const float4* xr = (const float4*)(x + (long long)n * 16);
        half8* xw = (half8*)(xp + (long long)n * 16);
#pragma unroll
        for (int j = 0; j < 2; j++) {
            float4 a = xr[2 * j], c = xr[2 * j + 1];
            half8 hv;
            hv[0] = (_Float16)(a.x * dv); hv[1] = (_Float16)(a.y * dv);
            hv[2] = (_Float16)(a.z * dv); hv[3] = (_Float16)(a.w * dv);
            hv[4] = (_Float16)(c.x * dv); hv[5] = (_Float16)(c.y * dv);
            hv[6] = (_Float16)(c.z * dv); hv[7] = (_Float16)(c.w * dv);
            xw[j] = hv;
        }
    }
}

// ---- fused gather16 + 16->16 GEMM + silu: h1 = silu(y@W1+b1)*dinv (fp16 io) ----
// Edge-group eg owns a CONTIGUOUS quarter of the row, ILP8. Packed 4B csr.
__global__ __launch_bounds__(256) void k_gx1(const _Float16* __restrict__ h,
                                             const unsigned int* __restrict__ csr,
                                             const unsigned int* __restrict__ offs,
                                             const float* __restrict__ dinv,
                                             const float* __restrict__ W,
                                             const float* __restrict__ b,
                                             _Float16* __restrict__ out, int N) {
    __shared__ float Ws[16 * 16];
    __shared__ float bs[16];
    if (threadIdx.x < 256) Ws[threadIdx.x] = W[threadIdx.x];
    if (threadIdx.x < 16) bs[threadIdx.x] = b[threadIdx.x];
    __syncthreads();
    int n = blockIdx.x * 4 + (threadIdx.x >> 6);
    n = __builtin_amdgcn_readfirstlane(n);
    if (n >= N) return;
    int lane = threadIdx.x & 63;
    int d = lane & 15, eg = lane >> 4;
    unsigned op = offs[n];
    int p0 = op & 0x00FFFFFF;
    int len = op >> 24;
    int qs = p0 + ((len * eg) >> 2);
    int qe = p0 + ((len * (eg + 1)) >> 2);
    float acc = 0.0f;
    int p = qs;
    for (; p + 7 < qe; p += 8) {
        unsigned ee[8];
#pragma unroll
        for (int i = 0; i < 8; i++) ee[i] = csr[p + i];
        float vv[8];
#pragma unroll
        for (int i = 0; i < 8; i++) vv[i] = (float)h[psrc(ee[i]) * 16 + d];
#pragma unroll
        for (int i = 0; i < 8; i++) acc += pew(ee[i]) * vv[i];
    }
    if (p + 3 < qe) {
        unsigned e0 = csr[p], e1 = csr[p + 1], e2 = csr[p + 2], e3 = csr[p + 3];
        float v0 = (float)h[psrc(e0) * 16 + d], v1 = (float)h[psrc(e1) * 16 + d];
        float v2 = (float)h[psrc(e2) * 16 + d], v3 = (float)h[psrc(e3) * 16 + d];
        acc += pew(e0) * v0; acc += pew(e1) * v1;
        acc += pew(e2) * v2; acc += pew(e3) * v3;
        p += 4;
    }
    if (p + 1 < qe) {
        unsigned e0 = csr[p], e1 = csr[p + 1];
        acc += pew(e0) * (float)h[psrc(e0) * 16 + d];
        acc += pew(e1) * (float)h[psrc(e1) * 16 + d];
        p += 2;
    }
    if (p < qe) {
        unsigned e0 = csr[p];
        acc += pew(e0) * (float)h[psrc(e0) * 16 + d];
    }
    acc += __shfl_down(acc, 32, 64);
    acc += __shfl_down(acc, 16, 64);
    float dv = dinv[n];
    float yv = (acc + ((lane < 16) ? (float)h[n * 16 + lane] : 0.0f)) * dv;
    float o = bs[d];
#pragma unroll
    for (int k = 0; k < 16; k++) o += __shfl(yv, k, 64) * Ws[k * 16 + d];
    if (lane < 16) out[n * 16 + lane] = (_Float16)(silu_f(o) * dv);
}

// ---- fused gather16 + 16->64 GEMM + silu: h2 = silu(y@W2+b2)*dinv (fp16 io) ----
__global__ __launch_bounds__(256) void k_gx2(const _Float16* __restrict__ h,
                                             const unsigned int* __restrict__ csr,
                                             const unsigned int* __restrict__ offs,
                                             const float* __restrict__ dinv,
                                             const float* __restrict__ W,
                                             const float* __restrict__ b,
                                             _Float16* __restrict__ out, int N) {
    __shared__ float Ws[16 * 64];
    __shared__ float bs[64];
    for (int i = threadIdx.x; i < 16 * 64; i += 256) Ws[i] = W[i];
    if (threadIdx.x < 64) bs[threadIdx.x] = b[threadIdx.x];
    __syncthreads();
    int n = blockIdx.x * 4 + (threadIdx.x >> 6);
    n = __builtin_amdgcn_readfirstlane(n);
    if (n >= N) return;
    int lane = threadIdx.x & 63;
    int d = lane & 15, eg = lane >> 4;
    unsigned op = offs[n];
    int p0 = op & 0x00FFFFFF;
    int len = op >> 24;
    int qs = p0 + ((len * eg) >> 2);
    int qe = p0 + ((len * (eg + 1)) >> 2);
    float acc = 0.0f;
    int p = qs;
    for (; p + 7 < qe; p += 8) {
        unsigned ee[8];
#pragma unroll
        for (int i = 0; i < 8; i++) ee[i] = csr[p + i];
        float vv[8];
#pragma unroll
        for (int i = 0; i < 8; i++) vv[i] = (float)h[psrc(ee[i]) * 16 + d];
#pragma unroll
        for (int i = 0; i < 8; i++) acc += pew(ee[i]) * vv[i];
    }
    if (p + 3 < qe) {
        unsigned e0 = csr[p], e1 = csr[p + 1], e2 = csr[p + 2], e3 = csr[p + 3];
        float v0 = (float)h[psrc(e0) * 16 + d], v1 = (float)h[psrc(e1) * 16 + d];
        float v2 = (float)h[psrc(e2) * 16 + d], v3 = (float)h[psrc(e3) * 16 + d];
        acc += pew(e0) * v0; acc += pew(e1) * v1;
        acc += pew(e2) * v2; acc += pew(e3) * v3;
        p += 4;
    }
    if (p + 1 < qe) {
        unsigned e0 = csr[p], e1 = csr[p + 1];
        acc += pew(e0) * (float)h[psrc(e0) * 16 + d];
        acc += pew(e1) * (float)h[psrc(e1) * 16 + d];
        p += 2;
    }
    if (p < qe) {
        unsigned e0 = csr[p];
        acc += pew(e0) * (float)h[psrc(e0) * 16 + d];
    }
    acc += __shfl_down(acc, 32, 64);
    acc += __shfl_down(acc, 16, 64);
    float dv = dinv[n];
    float yv = (acc + ((lane < 16) ? (float)h[n * 16 + lane] : 0.0f)) * dv;
    float o = bs[lane];
#pragma unroll
    for (int k = 0; k < 16; k++) o += __shfl(yv, k, 64) * Ws[k * 64 + lane];
    out[(long long)n * 64 + lane] = (_Float16)(silu_f(o) * dv);
}

// ---- gather D=64: 2 edges/wave-step (lane = fp16x2 of one edge's row) ----
// lanes 0-31 = edge j, lanes 32-63 = edge j+1; entries via uniform scalar
// loads + cndmask; shfl_xor(32) combine; lanes 0-31 write 4B. 16 edges
// in flight at ILP8.
__global__ __launch_bounds__(256) void k_gather64(const _Float16* __restrict__ h,
                                                  const unsigned int* __restrict__ csr,
                                                  const unsigned int* __restrict__ offs,
                                                  const float* __restrict__ dinv,
                                                  _Float16* __restrict__ y, int N) {
    int n = blockIdx.x * 4 + (threadIdx.x >> 6);
    n = __builtin_amdgcn_readfirstlane(n);
    if (n >= N) return;
    int lane = threadIdx.x & 63;
    int hf = lane >> 5;
    int sub = lane & 31;
    unsigned op = offs[n];
    const unsigned* row = csr + (op & 0x00FFFFFF);
    int len = op >> 24;
    const _Float16* hb = h + 2 * sub;
    float a0 = 0.0f, a1 = 0.0f;
    int j = 0;
    for (; j + 15 < len; j += 16) {
        unsigned ent[8];
#pragma unroll
        for (int i = 0; i < 8; i++) {
            unsigned e0 = row[j + 2 * i], e1 = row[j + 2 * i + 1];
            ent[i] = hf ? e1 : e0;
        }
        half2v hv[8];
#pragma unroll
        for (int i = 0; i < 8; i++)
            hv[i] = *(const half2v*)(hb + (long long)psrc(ent[i]) * 64);
#pragma unroll
        for (int i = 0; i < 8; i++) {
            float w = pew(ent[i]);
            a0 += w * (float)hv[i][0];
            a1 += w * (float)hv[i][1];
        }
    }
    for (; j + 1 < len; j += 2) {
        unsigned e0 = row[j], e1 = row[j + 1];
        unsigned ent = hf ? e1 : e0;
        half2v hv = *(const half2v*)(hb + (long long)psrc(ent) * 64);
        float w = pew(ent);
        a0 += w * (float)hv[0];
        a1 += w * (float)hv[1];
    }
    if (j < len) {                          // odd tail: upper half contributes 0
        unsigned ent = row[j];
        half2v hv = *(const half2v*)(hb + (long long)psrc(ent) * 64);
        float w = hf ? 0.0f : pew(ent);
        a0 += w * (float)hv[0];
        a1 += w * (float)hv[1];
    }
    a0 += __shfl_xor(a0, 32, 64);
    a1 += __shfl_xor(a1, 32, 64);
    if (hf == 0) {
        float dv = dinv[n];
        half2v sv = *(const half2v*)(h + (long long)n * 64 + 2 * sub);
        half2v o;
        o[0] = (_Float16)((a0 + (float)sv[0]) * dv);
        o[1] = (_Float16)((a1 + (float)sv[1]) * dv);
        *(half2v*)(y + (long long)n * 64 + 2 * sub) = o;
    }
}

// ---- layer-3 via MFMA f16: GEMM [ce-cs,64]@[64,256] + bias + silu + pool ----
__global__ __launch_bounds__(256) void k_xform3pool(const _Float16* __restrict__ y,
                                                    const float* __restrict__ W,
                                                    const float* __restrict__ b,
                                                    const int* __restrict__ bounds,
                                                    float* __restrict__ partial,
                                                    int N) {
    int lane = threadIdx.x & 63;
    int wave = threadIdx.x >> 6;
    int g = blockIdx.x / POOL_C;
    int c = blockIdx.x % POOL_C;
    int s = bounds[g], e = bounds[g + 1];
    int len = e - s;
    int cs = s + (int)((long long)len * c / POOL_C);
    int ce = s + (int)((long long)len * (c + 1) / POOL_C);
    int lg = lane >> 4;        // lane-group (k-block for A/B, row-block for C)
    int lr = lane & 15;        // A row / B,C col

    half8 bf[4][2];            // [out-tile][kstep] W fragments, in registers
#pragma unroll
    for (int t = 0; t < 4; t++) {
        int col = (wave * 4 + t) * 16 + lr;
#pragma unroll
        for (int s2 = 0; s2 < 2; s2++) {
            half8 v;
#pragma unroll
            for (int j = 0; j < 8; j++)
                v[j] = (_Float16)W[(s2 * 32 + lg * 8 + j) * 256 + col];
            bf[t][s2] = v;
        }
    }
    float bias[4];
#pragma unroll
    for (int t = 0; t < 4; t++) bias[t] = b[(wave * 4 + t) * 16 + lr];

    float pacc[4] = {0.f, 0.f, 0.f, 0.f};

    for (int base = cs; base < ce; base += 16) {
        int node = base + lr;
        int cn = node < N ? node : N - 1;      // clamp addr; masked at pool
        const half8* arow = (const half8*)(y + (long long)cn * 64);
        half8 a0 = arow[lg];                   // k = 0..31, this group's 8
        half8 a1 = arow[4 + lg];               // k = 32..63
#pragma unroll
        for (int t = 0; t < 4; t++) {
            f32x4 acc = {0.f, 0.f, 0.f, 0.f};
            acc = __builtin_amdgcn_mfma_f32_16x16x32_f16(a0, bf[t][0], acc, 0, 0, 0);
            acc = __builtin_amdgcn_mfma_f32_16x16x32_f16(a1, bf[t][1], acc, 0, 0, 0);
#pragma unroll
            for (int r = 0; r < 4; r++) {
                int nrow = base + lg * 4 + r;  // C row -> node
                if (nrow < ce) pacc[t] += silu_f(acc[r] + bias[t]);
            }
        }
    }
    // reduce over the 4 row-groups: lanes sharing lr
#pragma unroll
    for (int t = 0; t < 4; t++) {
        pacc[t] += __shfl_xor(pacc[t], 16, 64);
        pacc[t] += __shfl_xor(pacc[t], 32, 64);
    }
    if (lane < 16) {
        float* pr = partial + (long long)blockIdx.x * 256 + wave * 64;
#pragma unroll
        for (int t = 0; t < 4; t++) pr[t * 16 + lane] = pacc[t];
    }
}

// ---- pool stage 2 + MLP ----
__global__ __launch_bounds__(256) void k_mlp(const float* __restrict__ partial,
                                             const int* __restrict__ bounds,
                                             const float* __restrict__ L1,
                                             const float* __restrict__ c1,
                                             const float* __restrict__ L2,
                                             const float* __restrict__ c2,
                                             const float* __restrict__ L3,
                                             const float* __restrict__ c3,
                                             float* __restrict__ out) {
    __shared__ float pooled[256];
    __shared__ float z1[128];
    __shared__ float z2[64];
    int g = blockIdx.x;
    int t = threadIdx.x;
    int cnt = bounds[g + 1] - bounds[g];
    float s = 0.0f;
    for (int c = 0; c < POOL_C; c++) s += partial[((long long)g * POOL_C + c) * 256 + t];
    pooled[t] = s / (float)(cnt > 0 ? cnt : 1);
    __syncthreads();
    if (t < 128) {
        float acc = c1[t];
        for (int k = 0; k < 256; k++) acc += pooled[k] * L1[k * 128 + t];
        z1[t] = silu_f(acc);
    }
    __syncthreads();
    if (t < 64) {
        float acc = c2[t];
        for (int k = 0; k < 128; k++) acc += z1[k] * L2[k * 64 + t];
        z2[t] = silu_f(acc);
    }
    __syncthreads();
    if (t < 3) {
        float acc = c3[t];
        for (int k = 0; k < 64; k++) acc += z2[k] * L3[k * 3 + t];
        out[g * 3 + t] = acc;
    }
}

extern "C" void kernel_launch(void* const* d_in, const int* in_sizes, int n_in,
                              void* d_out, int out_size, void* d_ws, size_t ws_size,
                              hipStream_t stream) {
    const float* x     = (const float*)d_in[0];
    const int*   ei    = (const int*)d_in[1];
    const float* ea    = (const float*)d_in[2];
    const int*   batch = (const int*)d_in[3];
    const float* W1 = (const float*)d_in[4];
    const float* b1 = (const float*)d_in[5];
    const float* W2 = (const float*)d_in[6];
    const float* b2 = (const float*)d_in[7];
    const float* W3 = (const float*)d_in[8];
    const float* b3 = (const float*)d_in[9];
    const float* L1 = (const float*)d_in[10];
    const float* c1 = (const float*)d_in[11];
    const float* L2 = (const float*)d_in[12];
    const float* c2 = (const float*)d_in[13];
    const float* L3 = (const float*)d_in[14];
    const float* c3 = (const float*)d_in[15];
    float* out = (float*)d_out;

    const int N = in_sizes[0] / 16;
    const int E = in_sizes[2];
    const int G = out_size / 3;
    const int* src = ei;
    const int* dst = ei + E;
    const int B = (N + 255) >> 8;               // buckets (<=512)
    const int NBH = (E + SLICE - 1) / SLICE;    // one 3328-edge slice per block

    char* ws = (char*)d_ws;
    size_t off = 0;
    auto alloc = [&](size_t bytes) -> void* {
        void* p = (void*)(ws + off);
        off += (bytes + 255) & ~(size_t)255;
        return p;
    };
    float*        dinv    = (float*)alloc((size_t)N * 4);
    unsigned int* offs    = (unsigned int*)alloc((size_t)N * 4);
    int*          btotal  = (int*)  alloc(512 * 4);
    int*          bounds  = (int*)  alloc((size_t)(G + 1) * 4);
    int2*         ebuf    = (int2*) alloc((size_t)B * CAP * 8);   // padded buckets
    unsigned int* csr     = (unsigned int*)alloc((size_t)B * CAP * 4); // packed CSR
    _Float16*     xp      = (_Float16*)alloc((size_t)N * 16 * 2);
    _Float16*     h1s     = (_Float16*)alloc((size_t)N * 16 * 2);
    _Float16*     h2s     = (_Float16*)alloc((size_t)N * 64 * 2);
    _Float16*     y64     = (_Float16*)alloc((size_t)N * 64 * 2);
    float*        partial = (float*)alloc((size_t)G * POOL_C * 256 * 4);
    (void)ws_size;

    // ---- init, then single-kernel bucket scatter + node grouping ----
    k_init<<<1, 512, 0, stream>>>(batch, bounds, btotal, N, G);
    k_bscatter<<<NBH, 256, 0, stream>>>(src, dst, ea, btotal, ebuf, E, B);
    k_bucket_csr<<<B, 256, 0, stream>>>(ebuf, btotal, csr, offs, dinv, x, xp, N);

    // ---- layer 1 (fused gather+xform) ----
    k_gx1<<<(N + 3) / 4, 256, 0, stream>>>(xp, csr, offs, dinv, W1, b1, h1s, N);

    // ---- layer 2 (fused gather+xform) ----
    k_gx2<<<(N + 3) / 4, 256, 0, stream>>>(h1s, csr, offs, dinv, W2, b2, h2s, N);

    // ---- layer 3: gather fp16, then MFMA GEMM+silu+pool (h3 never written) ----
    k_gather64<<<(N + 3) / 4, 256, 0, stream>>>(h2s, csr, offs, dinv, y64, N);
    k_xform3pool<<<G * POOL_C, 256, 0, stream>>>(y64, W3, b3, bounds, partial, N);

    // ---- MLP head ----
    k_mlp<<<G, 256, 0, stream>>>(partial, bounds, L1, c1, L2, c2, L3, c3, out);
}